// Round 6
// baseline (2121.117 us; speedup 1.0000x reference)
//
#include <hip/hip_runtime.h>

#define BATCH 8
#define SEQ 4096
#define DIM 256
#define NH 8
#define DH 32
#define FFN_DIM 1024
#define NL 6
#define M_TOTAL (BATCH * SEQ)   // 32768
#define NCHUNK 8
#define FFN_ROWS 16384          // FFN M-chunk (hidden = 16384x1024 bf16 = 33.55 MB = BIG)

typedef __attribute__((ext_vector_type(8))) short s16x8;
typedef __attribute__((ext_vector_type(4))) short s16x4;
typedef __attribute__((ext_vector_type(4))) float f32x4;

__device__ __forceinline__ float bf2f(short s) {
    union { unsigned u; float f; } x;
    x.u = ((unsigned)(unsigned short)s) << 16;
    return x.f;
}
__device__ __forceinline__ short f2bf(float f) {
    union { float f; unsigned u; } x;
    x.f = f;
    unsigned r = x.u + 0x7fffu + ((x.u >> 16) & 1u);
    return (short)(r >> 16);
}

#define GLDS16(gp, sp) __builtin_amdgcn_global_load_lds( \
    (const __attribute__((address_space(1))) void*)(gp), \
    (__attribute__((address_space(3))) void*)(sp), 16, 0, 0)

// ---------------- positional encoding add: bf16 + fp32 dual write ----------------
__global__ void peadd_kernel(const float* __restrict__ Q, short* __restrict__ xb,
                             float* __restrict__ xf, int total)
{
    const float c = 9.210340371976184f / 256.f;  // ln(1e4)/256
    for (int idx = blockIdx.x * 256 + threadIdx.x; idx < total; idx += gridDim.x * 256) {
        int d = idx & (DIM - 1);
        int l = (idx >> 8) & (SEQ - 1);
        float rate = __expf(-(float)(d & ~1) * c);
        float ang = (float)l * rate;
        float pe = (d & 1) ? cosf(ang) : sinf(ang);
        float v = Q[idx] + pe;
        xb[idx] = f2bf(v);
        xf[idx] = v;
    }
}

__global__ void kconv_kernel(const float* __restrict__ src, short* __restrict__ dst, int total)
{
    for (int idx = blockIdx.x * 256 + threadIdx.x; idx < total; idx += gridDim.x * 256)
        dst[idx] = f2bf(src[idx]);
}

// ---- weight transpose+convert: Wt[lstride*z + (rowoff+n)*K + k] = W[z][k][n] ----
__global__ void wtrans_kernel(const float* __restrict__ W, short* __restrict__ Wt,
                              int K, int N, int lstride, int rowoff)
{
    __shared__ float tile[32][33];
    int k0 = blockIdx.x * 32, n0 = blockIdx.y * 32;
    const float* Wl = W + (long)blockIdx.z * K * N;
    short* Wtl = Wt + (long)blockIdx.z * lstride;
    int tx = threadIdx.x, ty = threadIdx.y;
#pragma unroll
    for (int r = 0; r < 4; ++r)
        tile[ty + r * 8][tx] = Wl[(long)(k0 + ty + r * 8) * N + n0 + tx];
    __syncthreads();
#pragma unroll
    for (int r = 0; r < 4; ++r)
        Wtl[(long)(rowoff + n0 + ty + r * 8) * K + k0 + tx] = f2bf(tile[tx][ty + r * 8]);
}

// ---- bias pack: bkv[z][0:256]=bk[z], [256:512]=bv[z] for both attn stacks ----
__global__ void bpack_kernel(const float* __restrict__ bk1, const float* __restrict__ bv1,
                             const float* __restrict__ bk2, const float* __restrict__ bv2,
                             float* __restrict__ o1, float* __restrict__ o2)
{
    int z = blockIdx.x, t = threadIdx.x;
    o1[z * 512 + t] = (t < 256) ? bk1[z * 256 + t] : bv1[z * 256 + t - 256];
    o2[z * 512 + t] = (t < 256) ? bk2[z * 256 + t] : bv2[z * 256 + t - 256];
}

// ---------------- bf16 MFMA GEMM: Cb = act(A @ Bt^T + bias), bf16 out -------------
// A: (M,K) bf16, row stride lda. Bt: (N,K) bf16. ACT: 0 none, 1 elu+1 for col<eluCut, 2 relu.
template<int ACT>
__global__ __launch_bounds__(256, 2) void gemm_bt_kernel(
    const short* __restrict__ A, const short* __restrict__ Bt,
    const float* __restrict__ bias, short* __restrict__ Cb,
    int N, int K, int lda, int ldc, int eluCut)
{
    __shared__ short As[4][128][8];   // [k-group][row][8 k-elems]
    __shared__ short Bs[4][128][8];
    const int tid = threadIdx.x;
    const int lane = tid & 63;
    const int wid = tid >> 6;
    const int wr = wid >> 1, wc = wid & 1;
    const int bm = blockIdx.x * 128, bn = blockIdx.y * 128;
    const int l15 = lane & 15, l4 = lane >> 4;

    const short* aSrc0 = A + (long)(bm + lane) * lda + wid * 8;
    const short* aSrc1 = A + (long)(bm + 64 + lane) * lda + wid * 8;
    const short* bSrc0 = Bt + (long)(bn + lane) * K + wid * 8;
    const short* bSrc1 = Bt + (long)(bn + 64 + lane) * K + wid * 8;

    f32x4 acc[4][4] = {};

    for (int k0 = 0; k0 < K; k0 += 32) {
        GLDS16(aSrc0 + k0, &As[wid][0][0]);
        GLDS16(aSrc1 + k0, &As[wid][64][0]);
        GLDS16(bSrc0 + k0, &Bs[wid][0][0]);
        GLDS16(bSrc1 + k0, &Bs[wid][64][0]);
        __syncthreads();
        s16x8 avA[4], avB[4];
#pragma unroll
        for (int m = 0; m < 4; ++m)
            avA[m] = *(const s16x8*)&As[l4][wr * 64 + m * 16 + l15][0];
#pragma unroll
        for (int n = 0; n < 4; ++n)
            avB[n] = *(const s16x8*)&Bs[l4][wc * 64 + n * 16 + l15][0];
#pragma unroll
        for (int m = 0; m < 4; ++m)
#pragma unroll
            for (int n = 0; n < 4; ++n)
                acc[m][n] = __builtin_amdgcn_mfma_f32_16x16x32_bf16(avA[m], avB[n], acc[m][n], 0, 0, 0);
        __syncthreads();
    }

#pragma unroll
    for (int m = 0; m < 4; ++m) {
        int row0 = bm + wr * 64 + m * 16 + l4 * 4;
#pragma unroll
        for (int n = 0; n < 4; ++n) {
            int col = bn + wc * 64 + n * 16 + l15;
            float bv = bias[col];
#pragma unroll
            for (int j = 0; j < 4; ++j) {
                float v = acc[m][n][j] + bv;
                if (ACT == 1) { if (col < eluCut) v = (v > 0.f) ? v + 1.f : __expf(v); }
                else if (ACT == 2) v = fmaxf(v, 0.f);
                Cb[(long)(row0 + j) * ldc + col] = f2bf(v);
            }
        }
    }
}

// ---- fused GEMM + bias + act + residual + LayerNorm (BM=64, BN=256, 8 waves) ----
// Depth-2 prefetch pipeline: BK=64, double-buffered LDS, raw s_barrier + counted
// vmcnt (each wave issues exactly 5 global_load_lds per K-tile: 40 slices / 8 waves).
// Ledger: vmcnt(5)+barrier => tile t landed for ALL waves (5 newest = tile t+1's);
// lgkmcnt(0)+barrier => all reads of buf done before STAGE(t+2) overwrites it;
// last iter waits vmcnt(0). "memory" clobbers pin LDS reads / DMA across barriers.
template<int ACT>
__global__ __launch_bounds__(512, 1) void gemmln_kernel(
    const short* __restrict__ A, const short* __restrict__ Bt,
    const float* __restrict__ bias,
    const float* __restrict__ gam, const float* __restrict__ bet,
    const float* __restrict__ Fin, float* __restrict__ Fout,
    short* __restrict__ xb, int K, int lda)
{
    __shared__ short As[2][8][64][8];    // 16 KB
    __shared__ short Bs[2][8][256][8];   // 64 KB
    __shared__ float partS[8][64];
    __shared__ float partQ[8][64];
    __shared__ float muA[64];
    __shared__ float rsA[64];
    const int tid = threadIdx.x;
    const int lane = tid & 63;
    const int w = tid >> 6;          // wave id 0..7; owns output cols [w*32, w*32+32)
    const int bm = blockIdx.x * 64;
    const int l15 = lane & 15, l4 = lane >> 4;
    const int nt = K >> 6;           // K-tiles of 64

    const short* aRow = A + (long)(bm + lane) * lda;

    // stage K-tile t into buffer buf: 40 wave-uniform slices, 5 per wave
    auto STAGE = [&](int buf, int t) {
        const int k0 = t << 6;
#pragma unroll
        for (int s5 = 0; s5 < 5; ++s5) {
            int s = w * 5 + s5;
            if (s < 8) {
                // A slice: k-group s, rows bm..bm+63
                GLDS16(aRow + k0 + s * 8, &As[buf][s][0][0]);
            } else {
                int bs = s - 8;
                int kg = bs & 7, rb = bs >> 3;
                GLDS16(Bt + (long)(rb * 64 + lane) * K + k0 + kg * 8, &Bs[buf][kg][rb * 64][0]);
            }
        }
    };

    f32x4 acc[4][2] = {};

    STAGE(0, 0);
    STAGE(1, 1);
    for (int t = 0; t < nt; ++t) {
        const int buf = t & 1;
        if (t + 1 < nt) { asm volatile("s_waitcnt vmcnt(5)" ::: "memory"); }
        else            { asm volatile("s_waitcnt vmcnt(0)" ::: "memory"); }
        asm volatile("s_barrier" ::: "memory");
        s16x8 avA[2][4], avB[2][2];
#pragma unroll
        for (int kk = 0; kk < 2; ++kk) {
#pragma unroll
            for (int m = 0; m < 4; ++m)
                avA[kk][m] = *(const s16x8*)&As[buf][kk * 4 + l4][m * 16 + l15][0];
#pragma unroll
            for (int n = 0; n < 2; ++n)
                avB[kk][n] = *(const s16x8*)&Bs[buf][kk * 4 + l4][w * 32 + n * 16 + l15][0];
        }
        asm volatile("s_waitcnt lgkmcnt(0)" ::: "memory");
        asm volatile("s_barrier" ::: "memory");
        if (t + 2 < nt) STAGE(buf, t + 2);
#pragma unroll
        for (int kk = 0; kk < 2; ++kk)
#pragma unroll
            for (int m = 0; m < 4; ++m)
#pragma unroll
                for (int n = 0; n < 2; ++n)
                    acc[m][n] = __builtin_amdgcn_mfma_f32_16x16x32_bf16(avA[kk][m], avB[kk][n], acc[m][n], 0, 0, 0);
    }

    // epilogue: bias + act + residual
#pragma unroll
    for (int m = 0; m < 4; ++m) {
#pragma unroll
        for (int n = 0; n < 2; ++n) {
            int col = w * 32 + n * 16 + l15;
            float bv = bias[col];
#pragma unroll
            for (int j = 0; j < 4; ++j) {
                int r = m * 16 + l4 * 4 + j;
                float v = acc[m][n][j] + bv;
                if (ACT == 2) v = fmaxf(v, 0.f);
                v += Fin[(long)(bm + r) * DIM + col];
                acc[m][n][j] = v;
            }
        }
    }
    // per-wave partial row sums (32 cols per wave)
#pragma unroll
    for (int m = 0; m < 4; ++m)
#pragma unroll
        for (int j = 0; j < 4; ++j) {
            float s = acc[m][0][j] + acc[m][1][j];
            float q = acc[m][0][j] * acc[m][0][j] + acc[m][1][j] * acc[m][1][j];
#pragma unroll
            for (int off = 1; off < 16; off <<= 1) {
                s += __shfl_xor(s, off);
                q += __shfl_xor(q, off);
            }
            if (l15 == 0) {
                partS[w][m * 16 + l4 * 4 + j] = s;
                partQ[w][m * 16 + l4 * 4 + j] = q;
            }
        }
    __syncthreads();
    if (tid < 64) {
        float S = 0, Qq = 0;
#pragma unroll
        for (int ww = 0; ww < 8; ++ww) { S += partS[ww][tid]; Qq += partQ[ww][tid]; }
        float mu = S * (1.f / 256.f);
        float var = Qq * (1.f / 256.f) - mu * mu;
        muA[tid] = mu;
        rsA[tid] = rsqrtf(var + 1e-3f);
    }
    __syncthreads();
#pragma unroll
    for (int m = 0; m < 4; ++m)
#pragma unroll
        for (int j = 0; j < 4; ++j) {
            int r = m * 16 + l4 * 4 + j;
            float mu = muA[r], rs = rsA[r];
#pragma unroll
            for (int n = 0; n < 2; ++n) {
                int col = w * 32 + n * 16 + l15;
                float t = (acc[m][n][j] - mu) * rs * gam[col] + bet[col];
                long o = (long)(bm + r) * DIM + col;
                xb[o] = f2bf(t);
                Fout[o] = t;
            }
        }
}

// ---------------- KV partial reduce: 512-row chunks, interleaved (M,512) KV buffer ----
__global__ __launch_bounds__(256) void kvpart_kernel(
    const short* __restrict__ KV, float* __restrict__ part)
{
    __shared__ float kfs[32][32];
    __shared__ float vsh[32][32];
    int c = blockIdx.x, bh = blockIdx.y;
    int b = bh >> 3, h = bh & 7;
    int tid = threadIdx.x;
    int d = tid >> 3, m0 = (tid & 7) * 4;
    float acc0 = 0, acc1 = 0, acc2 = 0, acc3 = 0, ks = 0;
    long rowBase = ((long)b * SEQ + c * 512) * 512 + h * DH;
    int lrow = (tid & 127) >> 2, cg = tid & 3;
    for (int s0 = 0; s0 < 512; s0 += 32) {
        long rb = rowBase + (long)(s0 + lrow) * 512 + cg * 8 + ((tid < 128) ? 0 : 256);
        s16x8 v8 = *(const s16x8*)(KV + rb);
        float* dst = (tid < 128) ? &kfs[lrow][cg * 8] : &vsh[lrow][cg * 8];
#pragma unroll
        for (int e = 0; e < 8; ++e) dst[e] = bf2f(v8[e]);
        __syncthreads();
#pragma unroll
        for (int s = 0; s < 32; ++s) {
            float kd = kfs[s][d];
            acc0 += kd * vsh[s][m0];
            acc1 += kd * vsh[s][m0 + 1];
            acc2 += kd * vsh[s][m0 + 2];
            acc3 += kd * vsh[s][m0 + 3];
        }
        if (tid < 32) {
#pragma unroll
            for (int s = 0; s < 32; ++s) ks += kfs[s][tid];
        }
        __syncthreads();
    }
    float* pb = part + ((long)bh * NCHUNK + c) * 1056;
    pb[tid * 4 + 0] = acc0; pb[tid * 4 + 1] = acc1;
    pb[tid * 4 + 2] = acc2; pb[tid * 4 + 3] = acc3;
    if (tid < 32) pb[1024 + tid] = ks;
}

__global__ __launch_bounds__(256) void kvred_kernel(
    const float* __restrict__ part, float* __restrict__ kv, float* __restrict__ ksum)
{
    int bh = blockIdx.x, tid = threadIdx.x;
    const float* pb = part + (long)bh * NCHUNK * 1056;
    float s0 = 0, s1 = 0, s2 = 0, s3 = 0;
    for (int cc = 0; cc < NCHUNK; ++cc) {
        const float* p = pb + cc * 1056 + tid * 4;
        s0 += p[0]; s1 += p[1]; s2 += p[2]; s3 += p[3];
    }
    float* kb = kv + (long)bh * 1024 + tid * 4;
    kb[0] = s0; kb[1] = s1; kb[2] = s2; kb[3] = s3;
    if (tid < 32) {
        float ss = 0;
        for (int cc = 0; cc < NCHUNK; ++cc) ss += pb[cc * 1056 + 1024 + tid];
        ksum[bh * 32 + tid] = ss;
    }
}

// ---------------- attention output: out = (Qf @ KV) * Z per (b,h); ld=512 -----------
__global__ __launch_bounds__(256) void attn_kernel(
    const short* __restrict__ Qf, const float* __restrict__ kv,
    const float* __restrict__ ksum, short* __restrict__ outp)
{
    __shared__ short kvbT[32][32];   // kvbT[m][d] = KV[d][m] bf16
    __shared__ float ksumf[32];
    __shared__ float zrow[128];
    const int LD = 512;
    int bh = blockIdx.y, b = bh >> 3, h = bh & 7;
    int l0 = blockIdx.x * 128;
    int tid = threadIdx.x;
    for (int j = tid; j < 1024; j += 256) {
        int dd = j >> 5, mm = j & 31;
        kvbT[mm][dd] = f2bf(kv[(long)bh * 1024 + j]);
    }
    if (tid < 32) ksumf[tid] = ksum[bh * 32 + tid];
    __syncthreads();
    if (tid < 128) {
        const s16x4* qp = (const s16x4*)(Qf + ((long)(b * SEQ + l0 + tid) * LD + h * DH));
        float den = 1e-6f;
#pragma unroll
        for (int jj = 0; jj < 8; ++jj) {
            s16x4 q4 = qp[jj];
#pragma unroll
            for (int e = 0; e < 4; ++e) den += bf2f(q4[e]) * ksumf[jj * 4 + e];
        }
        zrow[tid] = 1.f / den;
    }
    __syncthreads();
    int lane = tid & 63, wid = tid >> 6;
    int l15 = lane & 15, l4 = lane >> 4;
    s16x8 bfr[2];
#pragma unroll
    for (int n = 0; n < 2; ++n)
        bfr[n] = *(const s16x8*)&kvbT[n * 16 + l15][l4 * 8];
    f32x4 acc[2][2] = {};
#pragma unroll
    for (int m = 0; m < 2; ++m) {
        int rr = wid * 32 + m * 16 + l15;
        s16x8 a = *(const s16x8*)(Qf + ((long)(b * SEQ + l0 + rr) * LD + h * DH + l4 * 8));
#pragma unroll
        for (int n = 0; n < 2; ++n)
            acc[m][n] = __builtin_amdgcn_mfma_f32_16x16x32_bf16(a, bfr[n], acc[m][n], 0, 0, 0);
    }
#pragma unroll
    for (int m = 0; m < 2; ++m)
#pragma unroll
        for (int n = 0; n < 2; ++n)
#pragma unroll
            for (int j = 0; j < 4; ++j) {
                int rr = wid * 32 + m * 16 + l4 * 4 + j;
                int cc = n * 16 + l15;
                float v = acc[m][n][j] * zrow[rr];
                outp[(long)(b * SEQ + l0 + rr) * LD + h * DH + cc] = f2bf(v);
            }
}

// =======================================================================================
extern "C" void kernel_launch(void* const* d_in, const int* in_sizes, int n_in,
                              void* d_out, int out_size, void* d_ws, size_t ws_size,
                              hipStream_t stream)
{
    const float* Qin = (const float*)d_in[0];
    const float* Kin = (const float*)d_in[1];
    const float* Wq1 = (const float*)d_in[2];
    const float* Wk1 = (const float*)d_in[3];
    const float* Wv1 = (const float*)d_in[4];
    const float* Wo1 = (const float*)d_in[5];
    const float* bq1 = (const float*)d_in[6];
    const float* bk1 = (const float*)d_in[7];
    const float* bv1 = (const float*)d_in[8];
    const float* bo1 = (const float*)d_in[9];
    const float* Wq2 = (const float*)d_in[10];
    const float* Wk2 = (const float*)d_in[11];
    const float* Wv2 = (const float*)d_in[12];
    const float* Wo2 = (const float*)d_in[13];
    const float* bq2 = (const float*)d_in[14];
    const float* bk2 = (const float*)d_in[15];
    const float* bv2 = (const float*)d_in[16];
    const float* bo2 = (const float*)d_in[17];
    const float* Wf1 = (const float*)d_in[18];
    const float* bf1 = (const float*)d_in[19];
    const float* Wf2 = (const float*)d_in[20];
    const float* bf2 = (const float*)d_in[21];
    const float* ln1g = (const float*)d_in[22];
    const float* ln1b = (const float*)d_in[23];
    const float* ln2g = (const float*)d_in[24];
    const float* ln2b = (const float*)d_in[25];
    const float* ln3g = (const float*)d_in[26];
    const float* ln3b = (const float*)d_in[27];
    (void)in_sizes; (void)n_in; (void)out_size;

    const size_t NEED = 117841920ULL;   // proven budget from round 2; actual use ~115.8 MB
    if (ws_size < NEED) return;

    char* ws = (char*)d_ws;
    size_t off = 0;
    auto alloc = [&](size_t bytes) -> void* {
        void* p = ws + off;
        off = (off + bytes + 255) & ~(size_t)255;
        return p;
    };
    const size_t ACT_E = (size_t)M_TOTAL * DIM;  // 8388608 elems

    short* wkv1t = (short*)alloc((size_t)NL * 512 * 256 * 2);   // [Wk;Wv] stack, layer stride 512*256
    short* wkv2t = (short*)alloc((size_t)NL * 512 * 256 * 2);
    short* wq1t  = (short*)alloc((size_t)NL * 65536 * 2);
    short* wo1t  = (short*)alloc((size_t)NL * 65536 * 2);
    short* wq2t  = (short*)alloc((size_t)NL * 65536 * 2);
    short* wo2t  = (short*)alloc((size_t)NL * 65536 * 2);
    short* wf1t  = (short*)alloc((size_t)NL * 262144 * 2);
    short* wf2t  = (short*)alloc((size_t)NL * 262144 * 2);
    float* bkv1  = (float*)alloc((size_t)NL * 512 * 4);
    float* bkv2  = (float*)alloc((size_t)NL * 512 * 4);
    short* kbf = (short*)alloc(ACT_E * 2);          // K input as bf16
    short* A0  = (short*)alloc(ACT_E * 2);          // current x (bf16)
    short* BIG = (short*)alloc((size_t)M_TOTAL * 512 * 2);  // KV/Q/attnout | FFN hidden
    float* Fx  = (float*)alloc(ACT_E * 4);          // fp32 residual trunk
    float* part = (float*)alloc((size_t)64 * NCHUNK * 1056 * 4);
    float* kvb  = (float*)alloc((size_t)64 * 1024 * 4);
    float* ksb  = (float*)alloc((size_t)64 * 32 * 4);

    peadd_kernel<<<2048, 256, 0, stream>>>(Qin, A0, Fx, (int)ACT_E);
    kconv_kernel<<<2048, 256, 0, stream>>>(Kin, kbf, (int)ACT_E);
    wtrans_kernel<<<dim3(8, 8, NL), dim3(32, 8), 0, stream>>>(Wk1, wkv1t, 256, 256, 512 * 256, 0);
    wtrans_kernel<<<dim3(8, 8, NL), dim3(32, 8), 0, stream>>>(Wv1, wkv1t, 256, 256, 512 * 256, 256);
    wtrans_kernel<<<dim3(8, 8, NL), dim3(32, 8), 0, stream>>>(Wk2, wkv2t, 256, 256, 512 * 256, 0);
    wtrans_kernel<<<dim3(8, 8, NL), dim3(32, 8), 0, stream>>>(Wv2, wkv2t, 256, 256, 512 * 256, 256);
    wtrans_kernel<<<dim3(8, 8, NL), dim3(32, 8), 0, stream>>>(Wq1, wq1t, 256, 256, 65536, 0);
    wtrans_kernel<<<dim3(8, 8, NL), dim3(32, 8), 0, stream>>>(Wo1, wo1t, 256, 256, 65536, 0);
    wtrans_kernel<<<dim3(8, 8, NL), dim3(32, 8), 0, stream>>>(Wq2, wq2t, 256, 256, 65536, 0);
    wtrans_kernel<<<dim3(8, 8, NL), dim3(32, 8), 0, stream>>>(Wo2, wo2t, 256, 256, 65536, 0);
    wtrans_kernel<<<dim3(8, 32, NL), dim3(32, 8), 0, stream>>>(Wf1, wf1t, 256, 1024, 262144, 0);
    wtrans_kernel<<<dim3(32, 8, NL), dim3(32, 8), 0, stream>>>(Wf2, wf2t, 1024, 256, 262144, 0);
    bpack_kernel<<<NL, 512, 0, stream>>>(bk1, bv1, bk2, bv2, bkv1, bkv2);

    dim3 blk(256), blk512(512);

    for (int i = 0; i < NL; ++i) {
        const short* wkv1i = wkv1t + (size_t)i * 512 * 256;
        const short* wkv2i = wkv2t + (size_t)i * 512 * 256;
        const short* wq1i = wq1t + (size_t)i * 65536;
        const short* wo1i = wo1t + (size_t)i * 65536;
        const short* wq2i = wq2t + (size_t)i * 65536;
        const short* wo2i = wo2t + (size_t)i * 65536;
        const short* wf1i = wf1t + (size_t)i * 262144;
        const short* wf2i = wf2t + (size_t)i * 262144;

        // ---- self linear-attention (x1 -> x2)
        gemm_bt_kernel<1><<<dim3(256, 4), blk, 0, stream>>>(A0, wkv1i, bkv1 + i * 512, BIG, 512, 256, 256, 512, 256);
        kvpart_kernel<<<dim3(NCHUNK, 64), blk, 0, stream>>>(BIG, part);
        kvred_kernel<<<64, blk, 0, stream>>>(part, kvb, ksb);
        gemm_bt_kernel<1><<<dim3(256, 2), blk, 0, stream>>>(A0, wq1i, bq1 + i * 256, BIG, 256, 256, 256, 512, 256);
        attn_kernel<<<dim3(SEQ / 128, 64), blk, 0, stream>>>(BIG, kvb, ksb, BIG + 256);
        gemmln_kernel<0><<<M_TOTAL / 64, blk512, 0, stream>>>(BIG + 256, wo1i, bo1 + i * 256,
            ln1g + i * 256, ln1b + i * 256, Fx, Fx, A0, 256, 512);

        // ---- cross linear-attention (x2, K -> x3)
        gemm_bt_kernel<1><<<dim3(256, 4), blk, 0, stream>>>(kbf, wkv2i, bkv2 + i * 512, BIG, 512, 256, 256, 512, 256);
        kvpart_kernel<<<dim3(NCHUNK, 64), blk, 0, stream>>>(BIG, part);
        kvred_kernel<<<64, blk, 0, stream>>>(part, kvb, ksb);
        gemm_bt_kernel<1><<<dim3(256, 2), blk, 0, stream>>>(A0, wq2i, bq2 + i * 256, BIG, 256, 256, 256, 512, 256);
        attn_kernel<<<dim3(SEQ / 128, 64), blk, 0, stream>>>(BIG, kvb, ksb, BIG + 256);
        gemmln_kernel<0><<<M_TOTAL / 64, blk512, 0, stream>>>(BIG + 256, wo2i, bo2 + i * 256,
            ln2g + i * 256, ln2b + i * 256, Fx, Fx, A0, 256, 512);

        // ---- FFN (x3 -> x1'), 2 chunks of 16384 rows; hidden reuses BIG
        for (int c = 0; c < 2; ++c) {
            const size_t ro = (size_t)c * FFN_ROWS * DIM;
            gemm_bt_kernel<2><<<dim3(FFN_ROWS / 128, 8), blk, 0, stream>>>(
                A0 + ro, wf1i, bf1 + i * 1024, BIG, 1024, 256, 256, 1024, 0);
            float* foutC = ((i == NL - 1) ? (float*)d_out : Fx) + ro;
            gemmln_kernel<2><<<FFN_ROWS / 64, blk512, 0, stream>>>(BIG, wf2i, bf2 + i * 256,
                ln3g + i * 256, ln3b + i * 256, Fx + ro, foutC, A0 + ro, 1024, 1024);
        }
    }
}

// Round 7
// 1865.425 us; speedup vs baseline: 1.1371x; 1.1371x over previous
//
#include <hip/hip_runtime.h>

#define BATCH 8
#define SEQ 4096
#define DIM 256
#define NH 8
#define DH 32
#define FFN_DIM 1024
#define NL 6
#define M_TOTAL (BATCH * SEQ)   // 32768
#define NCHUNK 8
#define FFN_ROWS 16384          // FFN M-chunk (hidden = 16384x1024 bf16 = 33.55 MB = BIG)

typedef __attribute__((ext_vector_type(8))) short s16x8;
typedef __attribute__((ext_vector_type(4))) short s16x4;
typedef __attribute__((ext_vector_type(4))) float f32x4;

__device__ __forceinline__ float bf2f(short s) {
    union { unsigned u; float f; } x;
    x.u = ((unsigned)(unsigned short)s) << 16;
    return x.f;
}
__device__ __forceinline__ short f2bf(float f) {
    union { float f; unsigned u; } x;
    x.f = f;
    unsigned r = x.u + 0x7fffu + ((x.u >> 16) & 1u);
    return (short)(r >> 16);
}

#define GLDS16(gp, sp) __builtin_amdgcn_global_load_lds( \
    (const __attribute__((address_space(1))) void*)(gp), \
    (__attribute__((address_space(3))) void*)(sp), 16, 0, 0)

// ---------------- positional encoding add: bf16 + fp32 dual write ----------------
__global__ void peadd_kernel(const float* __restrict__ Q, short* __restrict__ xb,
                             float* __restrict__ xf, int total)
{
    const float c = 9.210340371976184f / 256.f;  // ln(1e4)/256
    for (int idx = blockIdx.x * 256 + threadIdx.x; idx < total; idx += gridDim.x * 256) {
        int d = idx & (DIM - 1);
        int l = (idx >> 8) & (SEQ - 1);
        float rate = __expf(-(float)(d & ~1) * c);
        float ang = (float)l * rate;
        float pe = (d & 1) ? cosf(ang) : sinf(ang);
        float v = Q[idx] + pe;
        xb[idx] = f2bf(v);
        xf[idx] = v;
    }
}

__global__ void kconv_kernel(const float* __restrict__ src, short* __restrict__ dst, int total)
{
    for (int idx = blockIdx.x * 256 + threadIdx.x; idx < total; idx += gridDim.x * 256)
        dst[idx] = f2bf(src[idx]);
}

// ---- weight transpose+convert: Wt[lstride*z + (rowoff+n)*K + k] = W[z][k][n] ----
__global__ void wtrans_kernel(const float* __restrict__ W, short* __restrict__ Wt,
                              int K, int N, int lstride, int rowoff)
{
    __shared__ float tile[32][33];
    int k0 = blockIdx.x * 32, n0 = blockIdx.y * 32;
    const float* Wl = W + (long)blockIdx.z * K * N;
    short* Wtl = Wt + (long)blockIdx.z * lstride;
    int tx = threadIdx.x, ty = threadIdx.y;
#pragma unroll
    for (int r = 0; r < 4; ++r)
        tile[ty + r * 8][tx] = Wl[(long)(k0 + ty + r * 8) * N + n0 + tx];
    __syncthreads();
#pragma unroll
    for (int r = 0; r < 4; ++r)
        Wtl[(long)(rowoff + n0 + ty + r * 8) * K + k0 + tx] = f2bf(tile[tx][ty + r * 8]);
}

// ---- bias pack: bkv[z][0:256]=bk[z], [256:512]=bv[z] for both attn stacks ----
__global__ void bpack_kernel(const float* __restrict__ bk1, const float* __restrict__ bv1,
                             const float* __restrict__ bk2, const float* __restrict__ bv2,
                             float* __restrict__ o1, float* __restrict__ o2)
{
    int z = blockIdx.x, t = threadIdx.x;
    o1[z * 512 + t] = (t < 256) ? bk1[z * 256 + t] : bv1[z * 256 + t - 256];
    o2[z * 512 + t] = (t < 256) ? bk2[z * 256 + t] : bv2[z * 256 + t - 256];
}

// ---------------- bf16 MFMA GEMM: Cb = act(A @ Bt^T + bias), bf16 out -------------
// A: (M,K) bf16, row stride lda. Bt: (N,K) bf16. ACT: 0 none, 1 elu+1 for col<eluCut, 2 relu.
template<int ACT>
__global__ __launch_bounds__(256, 2) void gemm_bt_kernel(
    const short* __restrict__ A, const short* __restrict__ Bt,
    const float* __restrict__ bias, short* __restrict__ Cb,
    int N, int K, int lda, int ldc, int eluCut)
{
    __shared__ short As[4][128][8];   // [k-group][row][8 k-elems]
    __shared__ short Bs[4][128][8];
    const int tid = threadIdx.x;
    const int lane = tid & 63;
    const int wid = tid >> 6;
    const int wr = wid >> 1, wc = wid & 1;
    const int bm = blockIdx.x * 128, bn = blockIdx.y * 128;
    const int l15 = lane & 15, l4 = lane >> 4;

    const short* aSrc0 = A + (long)(bm + lane) * lda + wid * 8;
    const short* aSrc1 = A + (long)(bm + 64 + lane) * lda + wid * 8;
    const short* bSrc0 = Bt + (long)(bn + lane) * K + wid * 8;
    const short* bSrc1 = Bt + (long)(bn + 64 + lane) * K + wid * 8;

    f32x4 acc[4][4] = {};

    for (int k0 = 0; k0 < K; k0 += 32) {
        GLDS16(aSrc0 + k0, &As[wid][0][0]);
        GLDS16(aSrc1 + k0, &As[wid][64][0]);
        GLDS16(bSrc0 + k0, &Bs[wid][0][0]);
        GLDS16(bSrc1 + k0, &Bs[wid][64][0]);
        __syncthreads();
        s16x8 avA[4], avB[4];
#pragma unroll
        for (int m = 0; m < 4; ++m)
            avA[m] = *(const s16x8*)&As[l4][wr * 64 + m * 16 + l15][0];
#pragma unroll
        for (int n = 0; n < 4; ++n)
            avB[n] = *(const s16x8*)&Bs[l4][wc * 64 + n * 16 + l15][0];
#pragma unroll
        for (int m = 0; m < 4; ++m)
#pragma unroll
            for (int n = 0; n < 4; ++n)
                acc[m][n] = __builtin_amdgcn_mfma_f32_16x16x32_bf16(avA[m], avB[n], acc[m][n], 0, 0, 0);
        __syncthreads();
    }

#pragma unroll
    for (int m = 0; m < 4; ++m) {
        int row0 = bm + wr * 64 + m * 16 + l4 * 4;
#pragma unroll
        for (int n = 0; n < 4; ++n) {
            int col = bn + wc * 64 + n * 16 + l15;
            float bv = bias[col];
#pragma unroll
            for (int j = 0; j < 4; ++j) {
                float v = acc[m][n][j] + bv;
                if (ACT == 1) { if (col < eluCut) v = (v > 0.f) ? v + 1.f : __expf(v); }
                else if (ACT == 2) v = fmaxf(v, 0.f);
                Cb[(long)(row0 + j) * ldc + col] = f2bf(v);
            }
        }
    }
}

// ---- fused GEMM + bias + act + residual + LayerNorm (BM=64, BN=256, 8 waves) ----
// Row-major 128B-row LDS tiles with XOR swizzle (chunk ^= row&7): each
// global_load_lds covers 8 rows x 128B contiguous => 8 full-line txns/instr
// (8x fewer than the kg-major 16B-gather layout). Swizzle applied on BOTH
// sides (pre-swizzled global source + swizzled ds_read) per both-or-neither.
// Depth-2 prefetch, raw s_barrier + counted vmcnt(5) (5 loads/wave/tile).
template<int ACT>
__global__ __launch_bounds__(512, 1) void gemmln_kernel(
    const short* __restrict__ A, const short* __restrict__ Bt,
    const float* __restrict__ bias,
    const float* __restrict__ gam, const float* __restrict__ bet,
    const float* __restrict__ Fin, float* __restrict__ Fout,
    short* __restrict__ xb, int K, int lda)
{
    __shared__ short As[2][64][64];      // [buf][row][64 k-elems] = 16 KB
    __shared__ short Bs[2][256][64];     // 64 KB
    __shared__ float partS[8][64];
    __shared__ float partQ[8][64];
    __shared__ float muA[64];
    __shared__ float rsA[64];
    const int tid = threadIdx.x;
    const int lane = tid & 63;
    const int w = tid >> 6;          // wave id 0..7; owns output cols [w*32, w*32+32)
    const int bm = blockIdx.x * 64;
    const int l15 = lane & 15, l4 = lane >> 4;
    const int nt = K >> 6;           // K-tiles of 64
    const int rl = lane >> 3;        // row within 8-row staging group
    const int ch = lane & 7;         // 16B chunk within 128B row segment

    // stage K-tile t into buffer buf: 40 slices of (8 rows x 128B), 5 per wave
    auto STAGE = [&](int buf, int t) {
        const int k0 = t << 6;
#pragma unroll
        for (int s5 = 0; s5 < 5; ++s5) {
            int s = w * 5 + s5;
            if (s < 8) {
                int r = s * 8 + rl;                       // A row 0..63
                int cs = ch ^ (r & 7);                    // swizzled source chunk
                GLDS16(A + (long)(bm + r) * lda + k0 + cs * 8, &As[buf][s * 8][0]);
            } else {
                int r = (s - 8) * 8 + rl;                 // B row 0..255
                int cs = ch ^ (r & 7);
                GLDS16(Bt + (long)r * K + k0 + cs * 8, &Bs[buf][(s - 8) * 8][0]);
            }
        }
    };

    f32x4 acc[4][2] = {};

    STAGE(0, 0);
    STAGE(1, 1);
    for (int t = 0; t < nt; ++t) {
        const int buf = t & 1;
        if (t + 1 < nt) { asm volatile("s_waitcnt vmcnt(5)" ::: "memory"); }
        else            { asm volatile("s_waitcnt vmcnt(0)" ::: "memory"); }
        asm volatile("s_barrier" ::: "memory");
        s16x8 avA[2][4], avB[2][2];
        const int sw = l15 & 7;      // read-side swizzle (row&7 == l15&7 for all rows used)
#pragma unroll
        for (int kk = 0; kk < 2; ++kk) {
#pragma unroll
            for (int m = 0; m < 4; ++m)
                avA[kk][m] = *(const s16x8*)&As[buf][m * 16 + l15][(((kk << 2) | l4) ^ sw) << 3];
#pragma unroll
            for (int n = 0; n < 2; ++n)
                avB[kk][n] = *(const s16x8*)&Bs[buf][w * 32 + n * 16 + l15][(((kk << 2) | l4) ^ sw) << 3];
        }
        asm volatile("s_waitcnt lgkmcnt(0)" ::: "memory");
        asm volatile("s_barrier" ::: "memory");
        if (t + 2 < nt) STAGE(buf, t + 2);
#pragma unroll
        for (int kk = 0; kk < 2; ++kk)
#pragma unroll
            for (int m = 0; m < 4; ++m)
#pragma unroll
                for (int n = 0; n < 2; ++n)
                    acc[m][n] = __builtin_amdgcn_mfma_f32_16x16x32_bf16(avA[kk][m], avB[kk][n], acc[m][n], 0, 0, 0);
    }

    // epilogue: bias + act + residual
#pragma unroll
    for (int m = 0; m < 4; ++m) {
#pragma unroll
        for (int n = 0; n < 2; ++n) {
            int col = w * 32 + n * 16 + l15;
            float bv = bias[col];
#pragma unroll
            for (int j = 0; j < 4; ++j) {
                int r = m * 16 + l4 * 4 + j;
                float v = acc[m][n][j] + bv;
                if (ACT == 2) v = fmaxf(v, 0.f);
                v += Fin[(long)(bm + r) * DIM + col];
                acc[m][n][j] = v;
            }
        }
    }
    // per-wave partial row sums (32 cols per wave)
#pragma unroll
    for (int m = 0; m < 4; ++m)
#pragma unroll
        for (int j = 0; j < 4; ++j) {
            float s = acc[m][0][j] + acc[m][1][j];
            float q = acc[m][0][j] * acc[m][0][j] + acc[m][1][j] * acc[m][1][j];
#pragma unroll
            for (int off = 1; off < 16; off <<= 1) {
                s += __shfl_xor(s, off);
                q += __shfl_xor(q, off);
            }
            if (l15 == 0) {
                partS[w][m * 16 + l4 * 4 + j] = s;
                partQ[w][m * 16 + l4 * 4 + j] = q;
            }
        }
    __syncthreads();
    if (tid < 64) {
        float S = 0, Qq = 0;
#pragma unroll
        for (int ww = 0; ww < 8; ++ww) { S += partS[ww][tid]; Qq += partQ[ww][tid]; }
        float mu = S * (1.f / 256.f);
        float var = Qq * (1.f / 256.f) - mu * mu;
        muA[tid] = mu;
        rsA[tid] = rsqrtf(var + 1e-3f);
    }
    __syncthreads();
#pragma unroll
    for (int m = 0; m < 4; ++m)
#pragma unroll
        for (int j = 0; j < 4; ++j) {
            int r = m * 16 + l4 * 4 + j;
            float mu = muA[r], rs = rsA[r];
#pragma unroll
            for (int n = 0; n < 2; ++n) {
                int col = w * 32 + n * 16 + l15;
                float t = (acc[m][n][j] - mu) * rs * gam[col] + bet[col];
                long o = (long)(bm + r) * DIM + col;
                xb[o] = f2bf(t);
                Fout[o] = t;
            }
        }
}

// ---------------- KV partial reduce: 512-row chunks, interleaved (M,512) KV buffer ----
__global__ __launch_bounds__(256) void kvpart_kernel(
    const short* __restrict__ KV, float* __restrict__ part)
{
    __shared__ float kfs[32][32];
    __shared__ float vsh[32][32];
    int c = blockIdx.x, bh = blockIdx.y;
    int b = bh >> 3, h = bh & 7;
    int tid = threadIdx.x;
    int d = tid >> 3, m0 = (tid & 7) * 4;
    float acc0 = 0, acc1 = 0, acc2 = 0, acc3 = 0, ks = 0;
    long rowBase = ((long)b * SEQ + c * 512) * 512 + h * DH;
    int lrow = (tid & 127) >> 2, cg = tid & 3;
    for (int s0 = 0; s0 < 512; s0 += 32) {
        long rb = rowBase + (long)(s0 + lrow) * 512 + cg * 8 + ((tid < 128) ? 0 : 256);
        s16x8 v8 = *(const s16x8*)(KV + rb);
        float* dst = (tid < 128) ? &kfs[lrow][cg * 8] : &vsh[lrow][cg * 8];
#pragma unroll
        for (int e = 0; e < 8; ++e) dst[e] = bf2f(v8[e]);
        __syncthreads();
#pragma unroll
        for (int s = 0; s < 32; ++s) {
            float kd = kfs[s][d];
            acc0 += kd * vsh[s][m0];
            acc1 += kd * vsh[s][m0 + 1];
            acc2 += kd * vsh[s][m0 + 2];
            acc3 += kd * vsh[s][m0 + 3];
        }
        if (tid < 32) {
#pragma unroll
            for (int s = 0; s < 32; ++s) ks += kfs[s][tid];
        }
        __syncthreads();
    }
    float* pb = part + ((long)bh * NCHUNK + c) * 1056;
    pb[tid * 4 + 0] = acc0; pb[tid * 4 + 1] = acc1;
    pb[tid * 4 + 2] = acc2; pb[tid * 4 + 3] = acc3;
    if (tid < 32) pb[1024 + tid] = ks;
}

__global__ __launch_bounds__(256) void kvred_kernel(
    const float* __restrict__ part, float* __restrict__ kv, float* __restrict__ ksum)
{
    int bh = blockIdx.x, tid = threadIdx.x;
    const float* pb = part + (long)bh * NCHUNK * 1056;
    float s0 = 0, s1 = 0, s2 = 0, s3 = 0;
    for (int cc = 0; cc < NCHUNK; ++cc) {
        const float* p = pb + cc * 1056 + tid * 4;
        s0 += p[0]; s1 += p[1]; s2 += p[2]; s3 += p[3];
    }
    float* kb = kv + (long)bh * 1024 + tid * 4;
    kb[0] = s0; kb[1] = s1; kb[2] = s2; kb[3] = s3;
    if (tid < 32) {
        float ss = 0;
        for (int cc = 0; cc < NCHUNK; ++cc) ss += pb[cc * 1056 + 1024 + tid];
        ksum[bh * 32 + tid] = ss;
    }
}

// ---------------- attention output: out = (Qf @ KV) * Z per (b,h); ld=512 -----------
__global__ __launch_bounds__(256) void attn_kernel(
    const short* __restrict__ Qf, const float* __restrict__ kv,
    const float* __restrict__ ksum, short* __restrict__ outp)
{
    __shared__ short kvbT[32][32];   // kvbT[m][d] = KV[d][m] bf16
    __shared__ float ksumf[32];
    __shared__ float zrow[128];
    const int LD = 512;
    int bh = blockIdx.y, b = bh >> 3, h = bh & 7;
    int l0 = blockIdx.x * 128;
    int tid = threadIdx.x;
    for (int j = tid; j < 1024; j += 256) {
        int dd = j >> 5, mm = j & 31;
        kvbT[mm][dd] = f2bf(kv[(long)bh * 1024 + j]);
    }
    if (tid < 32) ksumf[tid] = ksum[bh * 32 + tid];
    __syncthreads();
    if (tid < 128) {
        const s16x4* qp = (const s16x4*)(Qf + ((long)(b * SEQ + l0 + tid) * LD + h * DH));
        float den = 1e-6f;
#pragma unroll
        for (int jj = 0; jj < 8; ++jj) {
            s16x4 q4 = qp[jj];
#pragma unroll
            for (int e = 0; e < 4; ++e) den += bf2f(q4[e]) * ksumf[jj * 4 + e];
        }
        zrow[tid] = 1.f / den;
    }
    __syncthreads();
    int lane = tid & 63, wid = tid >> 6;
    int l15 = lane & 15, l4 = lane >> 4;
    s16x8 bfr[2];
#pragma unroll
    for (int n = 0; n < 2; ++n)
        bfr[n] = *(const s16x8*)&kvbT[n * 16 + l15][l4 * 8];
    f32x4 acc[2][2] = {};
#pragma unroll
    for (int m = 0; m < 2; ++m) {
        int rr = wid * 32 + m * 16 + l15;
        s16x8 a = *(const s16x8*)(Qf + ((long)(b * SEQ + l0 + rr) * LD + h * DH + l4 * 8));
#pragma unroll
        for (int n = 0; n < 2; ++n)
            acc[m][n] = __builtin_amdgcn_mfma_f32_16x16x32_bf16(a, bfr[n], acc[m][n], 0, 0, 0);
    }
#pragma unroll
    for (int m = 0; m < 2; ++m)
#pragma unroll
        for (int n = 0; n < 2; ++n)
#pragma unroll
            for (int j = 0; j < 4; ++j) {
                int rr = wid * 32 + m * 16 + l4 * 4 + j;
                int cc = n * 16 + l15;
                float v = acc[m][n][j] * zrow[rr];
                outp[(long)(b * SEQ + l0 + rr) * LD + h * DH + cc] = f2bf(v);
            }
}

// =======================================================================================
extern "C" void kernel_launch(void* const* d_in, const int* in_sizes, int n_in,
                              void* d_out, int out_size, void* d_ws, size_t ws_size,
                              hipStream_t stream)
{
    const float* Qin = (const float*)d_in[0];
    const float* Kin = (const float*)d_in[1];
    const float* Wq1 = (const float*)d_in[2];
    const float* Wk1 = (const float*)d_in[3];
    const float* Wv1 = (const float*)d_in[4];
    const float* Wo1 = (const float*)d_in[5];
    const float* bq1 = (const float*)d_in[6];
    const float* bk1 = (const float*)d_in[7];
    const float* bv1 = (const float*)d_in[8];
    const float* bo1 = (const float*)d_in[9];
    const float* Wq2 = (const float*)d_in[10];
    const float* Wk2 = (const float*)d_in[11];
    const float* Wv2 = (const float*)d_in[12];
    const float* Wo2 = (const float*)d_in[13];
    const float* bq2 = (const float*)d_in[14];
    const float* bk2 = (const float*)d_in[15];
    const float* bv2 = (const float*)d_in[16];
    const float* bo2 = (const float*)d_in[17];
    const float* Wf1 = (const float*)d_in[18];
    const float* bf1 = (const float*)d_in[19];
    const float* Wf2 = (const float*)d_in[20];
    const float* bf2 = (const float*)d_in[21];
    const float* ln1g = (const float*)d_in[22];
    const float* ln1b = (const float*)d_in[23];
    const float* ln2g = (const float*)d_in[24];
    const float* ln2b = (const float*)d_in[25];
    const float* ln3g = (const float*)d_in[26];
    const float* ln3b = (const float*)d_in[27];
    (void)in_sizes; (void)n_in; (void)out_size;

    const size_t NEED = 117841920ULL;   // proven budget from round 2; actual use ~115.8 MB
    if (ws_size < NEED) return;

    char* ws = (char*)d_ws;
    size_t off = 0;
    auto alloc = [&](size_t bytes) -> void* {
        void* p = ws + off;
        off = (off + bytes + 255) & ~(size_t)255;
        return p;
    };
    const size_t ACT_E = (size_t)M_TOTAL * DIM;  // 8388608 elems

    short* wkv1t = (short*)alloc((size_t)NL * 512 * 256 * 2);   // [Wk;Wv] stack, layer stride 512*256
    short* wkv2t = (short*)alloc((size_t)NL * 512 * 256 * 2);
    short* wq1t  = (short*)alloc((size_t)NL * 65536 * 2);
    short* wo1t  = (short*)alloc((size_t)NL * 65536 * 2);
    short* wq2t  = (short*)alloc((size_t)NL * 65536 * 2);
    short* wo2t  = (short*)alloc((size_t)NL * 65536 * 2);
    short* wf1t  = (short*)alloc((size_t)NL * 262144 * 2);
    short* wf2t  = (short*)alloc((size_t)NL * 262144 * 2);
    float* bkv1  = (float*)alloc((size_t)NL * 512 * 4);
    float* bkv2  = (float*)alloc((size_t)NL * 512 * 4);
    short* kbf = (short*)alloc(ACT_E * 2);          // K input as bf16
    short* A0  = (short*)alloc(ACT_E * 2);          // current x (bf16)
    short* BIG = (short*)alloc((size_t)M_TOTAL * 512 * 2);  // KV/Q/attnout | FFN hidden
    float* Fx  = (float*)alloc(ACT_E * 4);          // fp32 residual trunk
    float* part = (float*)alloc((size_t)64 * NCHUNK * 1056 * 4);
    float* kvb  = (float*)alloc((size_t)64 * 1024 * 4);
    float* ksb  = (float*)alloc((size_t)64 * 32 * 4);

    peadd_kernel<<<2048, 256, 0, stream>>>(Qin, A0, Fx, (int)ACT_E);
    kconv_kernel<<<2048, 256, 0, stream>>>(Kin, kbf, (int)ACT_E);
    wtrans_kernel<<<dim3(8, 8, NL), dim3(32, 8), 0, stream>>>(Wk1, wkv1t, 256, 256, 512 * 256, 0);
    wtrans_kernel<<<dim3(8, 8, NL), dim3(32, 8), 0, stream>>>(Wv1, wkv1t, 256, 256, 512 * 256, 256);
    wtrans_kernel<<<dim3(8, 8, NL), dim3(32, 8), 0, stream>>>(Wk2, wkv2t, 256, 256, 512 * 256, 0);
    wtrans_kernel<<<dim3(8, 8, NL), dim3(32, 8), 0, stream>>>(Wv2, wkv2t, 256, 256, 512 * 256, 256);
    wtrans_kernel<<<dim3(8, 8, NL), dim3(32, 8), 0, stream>>>(Wq1, wq1t, 256, 256, 65536, 0);
    wtrans_kernel<<<dim3(8, 8, NL), dim3(32, 8), 0, stream>>>(Wo1, wo1t, 256, 256, 65536, 0);
    wtrans_kernel<<<dim3(8, 8, NL), dim3(32, 8), 0, stream>>>(Wq2, wq2t, 256, 256, 65536, 0);
    wtrans_kernel<<<dim3(8, 8, NL), dim3(32, 8), 0, stream>>>(Wo2, wo2t, 256, 256, 65536, 0);
    wtrans_kernel<<<dim3(8, 32, NL), dim3(32, 8), 0, stream>>>(Wf1, wf1t, 256, 1024, 262144, 0);
    wtrans_kernel<<<dim3(32, 8, NL), dim3(32, 8), 0, stream>>>(Wf2, wf2t, 1024, 256, 262144, 0);
    bpack_kernel<<<NL, 512, 0, stream>>>(bk1, bv1, bk2, bv2, bkv1, bkv2);

    dim3 blk(256), blk512(512);

    for (int i = 0; i < NL; ++i) {
        const short* wkv1i = wkv1t + (size_t)i * 512 * 256;
        const short* wkv2i = wkv2t + (size_t)i * 512 * 256;
        const short* wq1i = wq1t + (size_t)i * 65536;
        const short* wo1i = wo1t + (size_t)i * 65536;
        const short* wq2i = wq2t + (size_t)i * 65536;
        const short* wo2i = wo2t + (size_t)i * 65536;
        const short* wf1i = wf1t + (size_t)i * 262144;
        const short* wf2i = wf2t + (size_t)i * 262144;

        // ---- self linear-attention (x1 -> x2)
        gemm_bt_kernel<1><<<dim3(256, 4), blk, 0, stream>>>(A0, wkv1i, bkv1 + i * 512, BIG, 512, 256, 256, 512, 256);
        kvpart_kernel<<<dim3(NCHUNK, 64), blk, 0, stream>>>(BIG, part);
        kvred_kernel<<<64, blk, 0, stream>>>(part, kvb, ksb);
        gemm_bt_kernel<1><<<dim3(256, 2), blk, 0, stream>>>(A0, wq1i, bq1 + i * 256, BIG, 256, 256, 256, 512, 256);
        attn_kernel<<<dim3(SEQ / 128, 64), blk, 0, stream>>>(BIG, kvb, ksb, BIG + 256);
        gemmln_kernel<0><<<M_TOTAL / 64, blk512, 0, stream>>>(BIG + 256, wo1i, bo1 + i * 256,
            ln1g + i * 256, ln1b + i * 256, Fx, Fx, A0, 256, 512);

        // ---- cross linear-attention (x2, K -> x3)
        gemm_bt_kernel<1><<<dim3(256, 4), blk, 0, stream>>>(kbf, wkv2i, bkv2 + i * 512, BIG, 512, 256, 256, 512, 256);
        kvpart_kernel<<<dim3(NCHUNK, 64), blk, 0, stream>>>(BIG, part);
        kvred_kernel<<<64, blk, 0, stream>>>(part, kvb, ksb);
        gemm_bt_kernel<1><<<dim3(256, 2), blk, 0, stream>>>(A0, wq2i, bq2 + i * 256, BIG, 256, 256, 256, 512, 256);
        attn_kernel<<<dim3(SEQ / 128, 64), blk, 0, stream>>>(BIG, kvb, ksb, BIG + 256);
        gemmln_kernel<0><<<M_TOTAL / 64, blk512, 0, stream>>>(BIG + 256, wo2i, bo2 + i * 256,
            ln2g + i * 256, ln2b + i * 256, Fx, Fx, A0, 256, 512);

        // ---- FFN (x3 -> x1'), 2 chunks of 16384 rows; hidden reuses BIG
        for (int c = 0; c < 2; ++c) {
            const size_t ro = (size_t)c * FFN_ROWS * DIM;
            gemm_bt_kernel<2><<<dim3(FFN_ROWS / 128, 8), blk, 0, stream>>>(
                A0 + ro, wf1i, bf1 + i * 1024, BIG, 1024, 256, 256, 1024, 0);
            float* foutC = ((i == NL - 1) ? (float*)d_out : Fx) + ro;
            gemmln_kernel<2><<<FFN_ROWS / 64, blk512, 0, stream>>>(BIG, wf2i, bf2 + i * 256,
                ln3g + i * 256, ln3b + i * 256, Fx + ro, foutC, A0 + ro, 1024, 1024);
        }
    }
}

// Round 8
// 1641.791 us; speedup vs baseline: 1.2920x; 1.1362x over previous
//
#include <hip/hip_runtime.h>

#define BATCH 8
#define SEQ 4096
#define DIM 256
#define NH 8
#define DH 32
#define FFN_DIM 1024
#define NL 6
#define M_TOTAL (BATCH * SEQ)   // 32768
#define NCHUNK 8
#define FFN_ROWS 16384          // FFN M-chunk (hidden = 16384x1024 bf16 = 33.55 MB = BIG)

typedef __attribute__((ext_vector_type(8))) short s16x8;
typedef __attribute__((ext_vector_type(4))) short s16x4;
typedef __attribute__((ext_vector_type(4))) float f32x4;

__device__ __forceinline__ float bf2f(short s) {
    union { unsigned u; float f; } x;
    x.u = ((unsigned)(unsigned short)s) << 16;
    return x.f;
}
__device__ __forceinline__ short f2bf(float f) {
    union { float f; unsigned u; } x;
    x.f = f;
    unsigned r = x.u + 0x7fffu + ((x.u >> 16) & 1u);
    return (short)(r >> 16);
}

#define GLDS16(gp, sp) __builtin_amdgcn_global_load_lds( \
    (const __attribute__((address_space(1))) void*)(gp), \
    (__attribute__((address_space(3))) void*)(sp), 16, 0, 0)

// ---------------- positional encoding add: bf16 + fp32 dual write ----------------
__global__ void peadd_kernel(const float* __restrict__ Q, short* __restrict__ xb,
                             float* __restrict__ xf, int total)
{
    const float c = 9.210340371976184f / 256.f;  // ln(1e4)/256
    for (int idx = blockIdx.x * 256 + threadIdx.x; idx < total; idx += gridDim.x * 256) {
        int d = idx & (DIM - 1);
        int l = (idx >> 8) & (SEQ - 1);
        float rate = __expf(-(float)(d & ~1) * c);
        float ang = (float)l * rate;
        float pe = (d & 1) ? cosf(ang) : sinf(ang);
        float v = Q[idx] + pe;
        xb[idx] = f2bf(v);
        xf[idx] = v;
    }
}

__global__ void kconv_kernel(const float* __restrict__ src, short* __restrict__ dst, int total)
{
    for (int idx = blockIdx.x * 256 + threadIdx.x; idx < total; idx += gridDim.x * 256)
        dst[idx] = f2bf(src[idx]);
}

// ---- weight transpose+convert: Wt[lstride*z + (rowoff+n)*K + k] = W[z][k][n] ----
__global__ void wtrans_kernel(const float* __restrict__ W, short* __restrict__ Wt,
                              int K, int N, int lstride, int rowoff)
{
    __shared__ float tile[32][33];
    int k0 = blockIdx.x * 32, n0 = blockIdx.y * 32;
    const float* Wl = W + (long)blockIdx.z * K * N;
    short* Wtl = Wt + (long)blockIdx.z * lstride;
    int tx = threadIdx.x, ty = threadIdx.y;
#pragma unroll
    for (int r = 0; r < 4; ++r)
        tile[ty + r * 8][tx] = Wl[(long)(k0 + ty + r * 8) * N + n0 + tx];
    __syncthreads();
#pragma unroll
    for (int r = 0; r < 4; ++r)
        Wtl[(long)(rowoff + n0 + ty + r * 8) * K + k0 + tx] = f2bf(tile[tx][ty + r * 8]);
}

// ---- bias pack: bkv[z][0:256]=bk[z], [256:512]=bv[z] for both attn stacks ----
__global__ void bpack_kernel(const float* __restrict__ bk1, const float* __restrict__ bv1,
                             const float* __restrict__ bk2, const float* __restrict__ bv2,
                             float* __restrict__ o1, float* __restrict__ o2)
{
    int z = blockIdx.x, t = threadIdx.x;
    o1[z * 512 + t] = (t < 256) ? bk1[z * 256 + t] : bv1[z * 256 + t - 256];
    o2[z * 512 + t] = (t < 256) ? bk2[z * 256 + t] : bv2[z * 256 + t - 256];
}

// ---------------- bf16 MFMA GEMM: Cb = act(A @ Bt^T + bias), bf16 out -------------
// Coalesced row-major [row][64] LDS with XOR swizzle (both-sides: pre-swizzled
// global chunk + swizzled ds_read). BK=64, double-buffered, depth-2 prefetch,
// raw s_barrier + per-wave counted vmcnt(8) (32 slices / 4 waves).
template<int ACT>
__global__ __launch_bounds__(256, 2) void gemm_bt_kernel(
    const short* __restrict__ A, const short* __restrict__ Bt,
    const float* __restrict__ bias, short* __restrict__ Cb,
    int N, int K, int lda, int ldc, int eluCut)
{
    __shared__ short As[2][128][64];   // 32 KB
    __shared__ short Bs[2][128][64];   // 32 KB
    const int tid = threadIdx.x;
    const int lane = tid & 63;
    const int wid = tid >> 6;
    const int wr = wid >> 1, wc = wid & 1;
    const int bm = blockIdx.x * 128, bn = blockIdx.y * 128;
    const int l15 = lane & 15, l4 = lane >> 4;
    const int rl = lane >> 3;        // row within 8-row staging group
    const int ch = lane & 7;         // 16B chunk within 128B row
    const int nt = K >> 6;

    // stage K-tile t: 32 slices of (8 rows x 128B); wave wid does 8 slices
    auto STAGE = [&](int buf, int t) {
        const int k0 = t << 6;
#pragma unroll
        for (int j = 0; j < 8; ++j) {
            int s = wid * 8 + j;
            if (s < 16) {
                int r = s * 8 + rl;                       // A row 0..127
                int cs = ch ^ (r & 7);
                GLDS16(A + (long)(bm + r) * lda + k0 + cs * 8, &As[buf][s * 8][0]);
            } else {
                int r = (s - 16) * 8 + rl;                // B row 0..127
                int cs = ch ^ (r & 7);
                GLDS16(Bt + (long)(bn + r) * K + k0 + cs * 8, &Bs[buf][(s - 16) * 8][0]);
            }
        }
    };

    f32x4 acc[4][4] = {};

    STAGE(0, 0);
    STAGE(1, 1);
    for (int t = 0; t < nt; ++t) {
        const int buf = t & 1;
        if (t + 1 < nt) { asm volatile("s_waitcnt vmcnt(8)" ::: "memory"); }
        else            { asm volatile("s_waitcnt vmcnt(0)" ::: "memory"); }
        asm volatile("s_barrier" ::: "memory");
        s16x8 avA[2][4], avB[2][4];
        const int sw = l15 & 7;
#pragma unroll
        for (int kk = 0; kk < 2; ++kk) {
#pragma unroll
            for (int m = 0; m < 4; ++m)
                avA[kk][m] = *(const s16x8*)&As[buf][wr * 64 + m * 16 + l15][(((kk << 2) | l4) ^ sw) << 3];
#pragma unroll
            for (int n = 0; n < 4; ++n)
                avB[kk][n] = *(const s16x8*)&Bs[buf][wc * 64 + n * 16 + l15][(((kk << 2) | l4) ^ sw) << 3];
        }
        asm volatile("s_waitcnt lgkmcnt(0)" ::: "memory");
        asm volatile("s_barrier" ::: "memory");
        if (t + 2 < nt) STAGE(buf, t + 2);
#pragma unroll
        for (int kk = 0; kk < 2; ++kk)
#pragma unroll
            for (int m = 0; m < 4; ++m)
#pragma unroll
                for (int n = 0; n < 4; ++n)
                    acc[m][n] = __builtin_amdgcn_mfma_f32_16x16x32_bf16(avA[kk][m], avB[kk][n], acc[m][n], 0, 0, 0);
    }

#pragma unroll
    for (int m = 0; m < 4; ++m) {
        int row0 = bm + wr * 64 + m * 16 + l4 * 4;
#pragma unroll
        for (int n = 0; n < 4; ++n) {
            int col = bn + wc * 64 + n * 16 + l15;
            float bv = bias[col];
#pragma unroll
            for (int j = 0; j < 4; ++j) {
                float v = acc[m][n][j] + bv;
                if (ACT == 1) { if (col < eluCut) v = (v > 0.f) ? v + 1.f : __expf(v); }
                else if (ACT == 2) v = fmaxf(v, 0.f);
                Cb[(long)(row0 + j) * ldc + col] = f2bf(v);
            }
        }
    }
}

// ---- fused GEMM + bias + act + residual + LayerNorm (BM=32, BN=256, 8 waves) ----
// BM=32 -> LDS 74.3KB -> 2 blocks/CU. 36 slices/tile: waves 0-3 stage 5,
// waves 4-7 stage 4; each waits its own vmcnt count (per-wave counter).
template<int ACT>
__global__ __launch_bounds__(512, 4) void gemmln_kernel(
    const short* __restrict__ A, const short* __restrict__ Bt,
    const float* __restrict__ bias,
    const float* __restrict__ gam, const float* __restrict__ bet,
    const float* __restrict__ Fin, float* __restrict__ Fout,
    short* __restrict__ xb, int K, int lda)
{
    __shared__ short As[2][32][64];      // 8 KB
    __shared__ short Bs[2][256][64];     // 64 KB
    __shared__ float partS[8][32];
    __shared__ float partQ[8][32];
    __shared__ float muA[32];
    __shared__ float rsA[32];
    const int tid = threadIdx.x;
    const int lane = tid & 63;
    const int w = tid >> 6;          // wave id 0..7; owns output cols [w*32, w*32+32)
    const int bm = blockIdx.x * 32;
    const int l15 = lane & 15, l4 = lane >> 4;
    const int nt = K >> 6;
    const int rl = lane >> 3;
    const int ch = lane & 7;

    // stage K-tile t: 36 slices of (8 rows x 128B); wave w does s = w, w+8, ...
    auto STAGE = [&](int buf, int t) {
        const int k0 = t << 6;
#pragma unroll
        for (int j = 0; j < 5; ++j) {
            int s = w + j * 8;
            if (s < 36) {
                if (s < 4) {
                    int r = s * 8 + rl;                   // A row 0..31
                    int cs = ch ^ (r & 7);
                    GLDS16(A + (long)(bm + r) * lda + k0 + cs * 8, &As[buf][s * 8][0]);
                } else {
                    int r = (s - 4) * 8 + rl;             // B row 0..255
                    int cs = ch ^ (r & 7);
                    GLDS16(Bt + (long)r * K + k0 + cs * 8, &Bs[buf][(s - 4) * 8][0]);
                }
            }
        }
    };

    f32x4 acc[2][2] = {};

    STAGE(0, 0);
    STAGE(1, 1);
    for (int t = 0; t < nt; ++t) {
        const int buf = t & 1;
        if (t + 1 < nt) {
            if (w < 4) { asm volatile("s_waitcnt vmcnt(5)" ::: "memory"); }
            else       { asm volatile("s_waitcnt vmcnt(4)" ::: "memory"); }
        } else {
            asm volatile("s_waitcnt vmcnt(0)" ::: "memory");
        }
        asm volatile("s_barrier" ::: "memory");
        s16x8 avA[2][2], avB[2][2];
        const int sw = l15 & 7;
#pragma unroll
        for (int kk = 0; kk < 2; ++kk) {
#pragma unroll
            for (int m = 0; m < 2; ++m)
                avA[kk][m] = *(const s16x8*)&As[buf][m * 16 + l15][(((kk << 2) | l4) ^ sw) << 3];
#pragma unroll
            for (int n = 0; n < 2; ++n)
                avB[kk][n] = *(const s16x8*)&Bs[buf][w * 32 + n * 16 + l15][(((kk << 2) | l4) ^ sw) << 3];
        }
        asm volatile("s_waitcnt lgkmcnt(0)" ::: "memory");
        asm volatile("s_barrier" ::: "memory");
        if (t + 2 < nt) STAGE(buf, t + 2);
#pragma unroll
        for (int kk = 0; kk < 2; ++kk)
#pragma unroll
            for (int m = 0; m < 2; ++m)
#pragma unroll
                for (int n = 0; n < 2; ++n)
                    acc[m][n] = __builtin_amdgcn_mfma_f32_16x16x32_bf16(avA[kk][m], avB[kk][n], acc[m][n], 0, 0, 0);
    }

    // epilogue: bias + act + residual
#pragma unroll
    for (int m = 0; m < 2; ++m) {
#pragma unroll
        for (int n = 0; n < 2; ++n) {
            int col = w * 32 + n * 16 + l15;
            float bv = bias[col];
#pragma unroll
            for (int j = 0; j < 4; ++j) {
                int r = m * 16 + l4 * 4 + j;
                float v = acc[m][n][j] + bv;
                if (ACT == 2) v = fmaxf(v, 0.f);
                v += Fin[(long)(bm + r) * DIM + col];
                acc[m][n][j] = v;
            }
        }
    }
    // per-wave partial row sums (32 cols per wave)
#pragma unroll
    for (int m = 0; m < 2; ++m)
#pragma unroll
        for (int j = 0; j < 4; ++j) {
            float s = acc[m][0][j] + acc[m][1][j];
            float q = acc[m][0][j] * acc[m][0][j] + acc[m][1][j] * acc[m][1][j];
#pragma unroll
            for (int off = 1; off < 16; off <<= 1) {
                s += __shfl_xor(s, off);
                q += __shfl_xor(q, off);
            }
            if (l15 == 0) {
                partS[w][m * 16 + l4 * 4 + j] = s;
                partQ[w][m * 16 + l4 * 4 + j] = q;
            }
        }
    __syncthreads();
    if (tid < 32) {
        float S = 0, Qq = 0;
#pragma unroll
        for (int ww = 0; ww < 8; ++ww) { S += partS[ww][tid]; Qq += partQ[ww][tid]; }
        float mu = S * (1.f / 256.f);
        float var = Qq * (1.f / 256.f) - mu * mu;
        muA[tid] = mu;
        rsA[tid] = rsqrtf(var + 1e-3f);
    }
    __syncthreads();
#pragma unroll
    for (int m = 0; m < 2; ++m)
#pragma unroll
        for (int j = 0; j < 4; ++j) {
            int r = m * 16 + l4 * 4 + j;
            float mu = muA[r], rs = rsA[r];
#pragma unroll
            for (int n = 0; n < 2; ++n) {
                int col = w * 32 + n * 16 + l15;
                float t = (acc[m][n][j] - mu) * rs * gam[col] + bet[col];
                long o = (long)(bm + r) * DIM + col;
                xb[o] = f2bf(t);
                Fout[o] = t;
            }
        }
}

// ---------------- KV partial reduce: 512-row chunks, interleaved (M,512) KV buffer ----
__global__ __launch_bounds__(256) void kvpart_kernel(
    const short* __restrict__ KV, float* __restrict__ part)
{
    __shared__ float kfs[32][32];
    __shared__ float vsh[32][32];
    int c = blockIdx.x, bh = blockIdx.y;
    int b = bh >> 3, h = bh & 7;
    int tid = threadIdx.x;
    int d = tid >> 3, m0 = (tid & 7) * 4;
    float acc0 = 0, acc1 = 0, acc2 = 0, acc3 = 0, ks = 0;
    long rowBase = ((long)b * SEQ + c * 512) * 512 + h * DH;
    int lrow = (tid & 127) >> 2, cg = tid & 3;
    for (int s0 = 0; s0 < 512; s0 += 32) {
        long rb = rowBase + (long)(s0 + lrow) * 512 + cg * 8 + ((tid < 128) ? 0 : 256);
        s16x8 v8 = *(const s16x8*)(KV + rb);
        float* dst = (tid < 128) ? &kfs[lrow][cg * 8] : &vsh[lrow][cg * 8];
#pragma unroll
        for (int e = 0; e < 8; ++e) dst[e] = bf2f(v8[e]);
        __syncthreads();
#pragma unroll
        for (int s = 0; s < 32; ++s) {
            float kd = kfs[s][d];
            acc0 += kd * vsh[s][m0];
            acc1 += kd * vsh[s][m0 + 1];
            acc2 += kd * vsh[s][m0 + 2];
            acc3 += kd * vsh[s][m0 + 3];
        }
        if (tid < 32) {
#pragma unroll
            for (int s = 0; s < 32; ++s) ks += kfs[s][tid];
        }
        __syncthreads();
    }
    float* pb = part + ((long)bh * NCHUNK + c) * 1056;
    pb[tid * 4 + 0] = acc0; pb[tid * 4 + 1] = acc1;
    pb[tid * 4 + 2] = acc2; pb[tid * 4 + 3] = acc3;
    if (tid < 32) pb[1024 + tid] = ks;
}

__global__ __launch_bounds__(256) void kvred_kernel(
    const float* __restrict__ part, float* __restrict__ kv, float* __restrict__ ksum)
{
    int bh = blockIdx.x, tid = threadIdx.x;
    const float* pb = part + (long)bh * NCHUNK * 1056;
    float s0 = 0, s1 = 0, s2 = 0, s3 = 0;
    for (int cc = 0; cc < NCHUNK; ++cc) {
        const float* p = pb + cc * 1056 + tid * 4;
        s0 += p[0]; s1 += p[1]; s2 += p[2]; s3 += p[3];
    }
    float* kb = kv + (long)bh * 1024 + tid * 4;
    kb[0] = s0; kb[1] = s1; kb[2] = s2; kb[3] = s3;
    if (tid < 32) {
        float ss = 0;
        for (int cc = 0; cc < NCHUNK; ++cc) ss += pb[cc * 1056 + 1024 + tid];
        ksum[bh * 32 + tid] = ss;
    }
}

// ---------------- attention output: out = (Qf @ KV) * Z per (b,h); ld=512 -----------
__global__ __launch_bounds__(256) void attn_kernel(
    const short* __restrict__ Qf, const float* __restrict__ kv,
    const float* __restrict__ ksum, short* __restrict__ outp)
{
    __shared__ short kvbT[32][32];   // kvbT[m][d] = KV[d][m] bf16
    __shared__ float ksumf[32];
    __shared__ float zrow[128];
    const int LD = 512;
    int bh = blockIdx.y, b = bh >> 3, h = bh & 7;
    int l0 = blockIdx.x * 128;
    int tid = threadIdx.x;
    for (int j = tid; j < 1024; j += 256) {
        int dd = j >> 5, mm = j & 31;
        kvbT[mm][dd] = f2bf(kv[(long)bh * 1024 + j]);
    }
    if (tid < 32) ksumf[tid] = ksum[bh * 32 + tid];
    __syncthreads();
    if (tid < 128) {
        const s16x4* qp = (const s16x4*)(Qf + ((long)(b * SEQ + l0 + tid) * LD + h * DH));
        float den = 1e-6f;
#pragma unroll
        for (int jj = 0; jj < 8; ++jj) {
            s16x4 q4 = qp[jj];
#pragma unroll
            for (int e = 0; e < 4; ++e) den += bf2f(q4[e]) * ksumf[jj * 4 + e];
        }
        zrow[tid] = 1.f / den;
    }
    __syncthreads();
    int lane = tid & 63, wid = tid >> 6;
    int l15 = lane & 15, l4 = lane >> 4;
    s16x8 bfr[2];
#pragma unroll
    for (int n = 0; n < 2; ++n)
        bfr[n] = *(const s16x8*)&kvbT[n * 16 + l15][l4 * 8];
    f32x4 acc[2][2] = {};
#pragma unroll
    for (int m = 0; m < 2; ++m) {
        int rr = wid * 32 + m * 16 + l15;
        s16x8 a = *(const s16x8*)(Qf + ((long)(b * SEQ + l0 + rr) * LD + h * DH + l4 * 8));
#pragma unroll
        for (int n = 0; n < 2; ++n)
            acc[m][n] = __builtin_amdgcn_mfma_f32_16x16x32_bf16(a, bfr[n], acc[m][n], 0, 0, 0);
    }
#pragma unroll
    for (int m = 0; m < 2; ++m)
#pragma unroll
        for (int n = 0; n < 2; ++n)
#pragma unroll
            for (int j = 0; j < 4; ++j) {
                int rr = wid * 32 + m * 16 + l4 * 4 + j;
                int cc = n * 16 + l15;
                float v = acc[m][n][j] * zrow[rr];
                outp[(long)(b * SEQ + l0 + rr) * LD + h * DH + cc] = f2bf(v);
            }
}

// =======================================================================================
extern "C" void kernel_launch(void* const* d_in, const int* in_sizes, int n_in,
                              void* d_out, int out_size, void* d_ws, size_t ws_size,
                              hipStream_t stream)
{
    const float* Qin = (const float*)d_in[0];
    const float* Kin = (const float*)d_in[1];
    const float* Wq1 = (const float*)d_in[2];
    const float* Wk1 = (const float*)d_in[3];
    const float* Wv1 = (const float*)d_in[4];
    const float* Wo1 = (const float*)d_in[5];
    const float* bq1 = (const float*)d_in[6];
    const float* bk1 = (const float*)d_in[7];
    const float* bv1 = (const float*)d_in[8];
    const float* bo1 = (const float*)d_in[9];
    const float* Wq2 = (const float*)d_in[10];
    const float* Wk2 = (const float*)d_in[11];
    const float* Wv2 = (const float*)d_in[12];
    const float* Wo2 = (const float*)d_in[13];
    const float* bq2 = (const float*)d_in[14];
    const float* bk2 = (const float*)d_in[15];
    const float* bv2 = (const float*)d_in[16];
    const float* bo2 = (const float*)d_in[17];
    const float* Wf1 = (const float*)d_in[18];
    const float* bf1 = (const float*)d_in[19];
    const float* Wf2 = (const float*)d_in[20];
    const float* bf2 = (const float*)d_in[21];
    const float* ln1g = (const float*)d_in[22];
    const float* ln1b = (const float*)d_in[23];
    const float* ln2g = (const float*)d_in[24];
    const float* ln2b = (const float*)d_in[25];
    const float* ln3g = (const float*)d_in[26];
    const float* ln3b = (const float*)d_in[27];
    (void)in_sizes; (void)n_in; (void)out_size;

    const size_t NEED = 117841920ULL;   // proven budget; actual use ~115.8 MB
    if (ws_size < NEED) return;

    char* ws = (char*)d_ws;
    size_t off = 0;
    auto alloc = [&](size_t bytes) -> void* {
        void* p = ws + off;
        off = (off + bytes + 255) & ~(size_t)255;
        return p;
    };
    const size_t ACT_E = (size_t)M_TOTAL * DIM;  // 8388608 elems

    short* wkv1t = (short*)alloc((size_t)NL * 512 * 256 * 2);   // [Wk;Wv] stack, layer stride 512*256
    short* wkv2t = (short*)alloc((size_t)NL * 512 * 256 * 2);
    short* wq1t  = (short*)alloc((size_t)NL * 65536 * 2);
    short* wo1t  = (short*)alloc((size_t)NL * 65536 * 2);
    short* wq2t  = (short*)alloc((size_t)NL * 65536 * 2);
    short* wo2t  = (short*)alloc((size_t)NL * 65536 * 2);
    short* wf1t  = (short*)alloc((size_t)NL * 262144 * 2);
    short* wf2t  = (short*)alloc((size_t)NL * 262144 * 2);
    float* bkv1  = (float*)alloc((size_t)NL * 512 * 4);
    float* bkv2  = (float*)alloc((size_t)NL * 512 * 4);
    short* kbf = (short*)alloc(ACT_E * 2);          // K input as bf16
    short* A0  = (short*)alloc(ACT_E * 2);          // current x (bf16)
    short* BIG = (short*)alloc((size_t)M_TOTAL * 512 * 2);  // KV/Q/attnout | FFN hidden
    float* Fx  = (float*)alloc(ACT_E * 4);          // fp32 residual trunk
    float* part = (float*)alloc((size_t)64 * NCHUNK * 1056 * 4);
    float* kvb  = (float*)alloc((size_t)64 * 1024 * 4);
    float* ksb  = (float*)alloc((size_t)64 * 32 * 4);

    peadd_kernel<<<2048, 256, 0, stream>>>(Qin, A0, Fx, (int)ACT_E);
    kconv_kernel<<<2048, 256, 0, stream>>>(Kin, kbf, (int)ACT_E);
    wtrans_kernel<<<dim3(8, 8, NL), dim3(32, 8), 0, stream>>>(Wk1, wkv1t, 256, 256, 512 * 256, 0);
    wtrans_kernel<<<dim3(8, 8, NL), dim3(32, 8), 0, stream>>>(Wv1, wkv1t, 256, 256, 512 * 256, 256);
    wtrans_kernel<<<dim3(8, 8, NL), dim3(32, 8), 0, stream>>>(Wk2, wkv2t, 256, 256, 512 * 256, 0);
    wtrans_kernel<<<dim3(8, 8, NL), dim3(32, 8), 0, stream>>>(Wv2, wkv2t, 256, 256, 512 * 256, 256);
    wtrans_kernel<<<dim3(8, 8, NL), dim3(32, 8), 0, stream>>>(Wq1, wq1t, 256, 256, 65536, 0);
    wtrans_kernel<<<dim3(8, 8, NL), dim3(32, 8), 0, stream>>>(Wo1, wo1t, 256, 256, 65536, 0);
    wtrans_kernel<<<dim3(8, 8, NL), dim3(32, 8), 0, stream>>>(Wq2, wq2t, 256, 256, 65536, 0);
    wtrans_kernel<<<dim3(8, 8, NL), dim3(32, 8), 0, stream>>>(Wo2, wo2t, 256, 256, 65536, 0);
    wtrans_kernel<<<dim3(8, 32, NL), dim3(32, 8), 0, stream>>>(Wf1, wf1t, 256, 1024, 262144, 0);
    wtrans_kernel<<<dim3(32, 8, NL), dim3(32, 8), 0, stream>>>(Wf2, wf2t, 1024, 256, 262144, 0);
    bpack_kernel<<<NL, 512, 0, stream>>>(bk1, bv1, bk2, bv2, bkv1, bkv2);

    dim3 blk(256), blk512(512);

    for (int i = 0; i < NL; ++i) {
        const short* wkv1i = wkv1t + (size_t)i * 512 * 256;
        const short* wkv2i = wkv2t + (size_t)i * 512 * 256;
        const short* wq1i = wq1t + (size_t)i * 65536;
        const short* wo1i = wo1t + (size_t)i * 65536;
        const short* wq2i = wq2t + (size_t)i * 65536;
        const short* wo2i = wo2t + (size_t)i * 65536;
        const short* wf1i = wf1t + (size_t)i * 262144;
        const short* wf2i = wf2t + (size_t)i * 262144;

        // ---- self linear-attention (x1 -> x2)
        gemm_bt_kernel<1><<<dim3(256, 4), blk, 0, stream>>>(A0, wkv1i, bkv1 + i * 512, BIG, 512, 256, 256, 512, 256);
        kvpart_kernel<<<dim3(NCHUNK, 64), blk, 0, stream>>>(BIG, part);
        kvred_kernel<<<64, blk, 0, stream>>>(part, kvb, ksb);
        gemm_bt_kernel<1><<<dim3(256, 2), blk, 0, stream>>>(A0, wq1i, bq1 + i * 256, BIG, 256, 256, 256, 512, 256);
        attn_kernel<<<dim3(SEQ / 128, 64), blk, 0, stream>>>(BIG, kvb, ksb, BIG + 256);
        gemmln_kernel<0><<<M_TOTAL / 32, blk512, 0, stream>>>(BIG + 256, wo1i, bo1 + i * 256,
            ln1g + i * 256, ln1b + i * 256, Fx, Fx, A0, 256, 512);

        // ---- cross linear-attention (x2, K -> x3)
        gemm_bt_kernel<1><<<dim3(256, 4), blk, 0, stream>>>(kbf, wkv2i, bkv2 + i * 512, BIG, 512, 256, 256, 512, 256);
        kvpart_kernel<<<dim3(NCHUNK, 64), blk, 0, stream>>>(BIG, part);
        kvred_kernel<<<64, blk, 0, stream>>>(part, kvb, ksb);
        gemm_bt_kernel<1><<<dim3(256, 2), blk, 0, stream>>>(A0, wq2i, bq2 + i * 256, BIG, 256, 256, 256, 512, 256);
        attn_kernel<<<dim3(SEQ / 128, 64), blk, 0, stream>>>(BIG, kvb, ksb, BIG + 256);
        gemmln_kernel<0><<<M_TOTAL / 32, blk512, 0, stream>>>(BIG + 256, wo2i, bo2 + i * 256,
            ln2g + i * 256, ln2b + i * 256, Fx, Fx, A0, 256, 512);

        // ---- FFN (x3 -> x1'), 2 chunks of 16384 rows; hidden reuses BIG
        for (int c = 0; c < 2; ++c) {
            const size_t ro = (size_t)c * FFN_ROWS * DIM;
            gemm_bt_kernel<2><<<dim3(FFN_ROWS / 128, 8), blk, 0, stream>>>(
                A0 + ro, wf1i, bf1 + i * 1024, BIG, 1024, 256, 256, 1024, 0);
            float* foutC = ((i == NL - 1) ? (float*)d_out : Fx) + ro;
            gemmln_kernel<2><<<FFN_ROWS / 32, blk512, 0, stream>>>(BIG, wf2i, bf2 + i * 256,
                ln3g + i * 256, ln3b + i * 256, Fx + ro, foutC, A0 + ro, 1024, 1024);
        }
    }
}

// Round 10
// 1574.071 us; speedup vs baseline: 1.3475x; 1.0430x over previous
//
#include <hip/hip_runtime.h>

#define BATCH 8
#define SEQ 4096
#define DIM 256
#define NH 8
#define DH 32
#define FFN_DIM 1024
#define NL 6
#define M_TOTAL (BATCH * SEQ)   // 32768
#define NCHUNK 8
#define FFN_ROWS 16384

typedef __attribute__((ext_vector_type(8))) short s16x8;
typedef __attribute__((ext_vector_type(4))) short s16x4;
typedef __attribute__((ext_vector_type(4))) float f32x4;

__device__ __forceinline__ float bf2f(short s) {
    union { unsigned u; float f; } x;
    x.u = ((unsigned)(unsigned short)s) << 16;
    return x.f;
}
__device__ __forceinline__ short f2bf(float f) {
    union { float f; unsigned u; } x;
    x.f = f;
    unsigned r = x.u + 0x7fffu + ((x.u >> 16) & 1u);
    return (short)(r >> 16);
}

#define GLDS16(gp, sp) __builtin_amdgcn_global_load_lds( \
    (const __attribute__((address_space(1))) void*)(gp), \
    (__attribute__((address_space(3))) void*)(sp), 16, 0, 0)

// ---------------- positional encoding add: bf16 + fp32 dual write ----------------
__global__ void peadd_kernel(const float* __restrict__ Q, short* __restrict__ xb,
                             float* __restrict__ xf, int total)
{
    const float c = 9.210340371976184f / 256.f;  // ln(1e4)/256
    for (int idx = blockIdx.x * 256 + threadIdx.x; idx < total; idx += gridDim.x * 256) {
        int d = idx & (DIM - 1);
        int l = (idx >> 8) & (SEQ - 1);
        float rate = __expf(-(float)(d & ~1) * c);
        float ang = (float)l * rate;
        float pe = (d & 1) ? cosf(ang) : sinf(ang);
        float v = Q[idx] + pe;
        xb[idx] = f2bf(v);
        xf[idx] = v;
    }
}

__global__ void kconv_kernel(const float* __restrict__ src, short* __restrict__ dst, int total)
{
    for (int idx = blockIdx.x * 256 + threadIdx.x; idx < total; idx += gridDim.x * 256)
        dst[idx] = f2bf(src[idx]);
}

// ---- weight transpose+convert: Wt[lstride*z + (rowoff+n)*K + k] = W[z][k][n] ----
__global__ void wtrans_kernel(const float* __restrict__ W, short* __restrict__ Wt,
                              int K, int N, int lstride, int rowoff)
{
    __shared__ float tile[32][33];
    int k0 = blockIdx.x * 32, n0 = blockIdx.y * 32;
    const float* Wl = W + (long)blockIdx.z * K * N;
    short* Wtl = Wt + (long)blockIdx.z * lstride;
    int tx = threadIdx.x, ty = threadIdx.y;
#pragma unroll
    for (int r = 0; r < 4; ++r)
        tile[ty + r * 8][tx] = Wl[(long)(k0 + ty + r * 8) * N + n0 + tx];
    __syncthreads();
#pragma unroll
    for (int r = 0; r < 4; ++r)
        Wtl[(long)(rowoff + n0 + ty + r * 8) * K + k0 + tx] = f2bf(tile[tx][ty + r * 8]);
}

// ---- bias pack ----
__global__ void bpack_kernel(const float* __restrict__ bk1, const float* __restrict__ bv1,
                             const float* __restrict__ bk2, const float* __restrict__ bv2,
                             float* __restrict__ o1, float* __restrict__ o2)
{
    int z = blockIdx.x, t = threadIdx.x;
    o1[z * 512 + t] = (t < 256) ? bk1[z * 256 + t] : bv1[z * 256 + t - 256];
    o2[z * 512 + t] = (t < 256) ? bk2[z * 256 + t] : bv2[z * 256 + t - 256];
}

// ---------------- bf16 MFMA GEMM (coalesced+swizzled staging, R8-proven) -------------
template<int ACT>
__global__ __launch_bounds__(256, 2) void gemm_bt_kernel(
    const short* __restrict__ A, const short* __restrict__ Bt,
    const float* __restrict__ bias, short* __restrict__ Cb,
    int N, int K, int lda, int ldc, int eluCut)
{
    __shared__ short As[2][128][64];
    __shared__ short Bs[2][128][64];
    const int tid = threadIdx.x;
    const int lane = tid & 63;
    const int wid = tid >> 6;
    const int wr = wid >> 1, wc = wid & 1;
    const int bm = blockIdx.x * 128, bn = blockIdx.y * 128;
    const int l15 = lane & 15, l4 = lane >> 4;
    const int rl = lane >> 3;
    const int ch = lane & 7;
    const int nt = K >> 6;

    auto STAGE = [&](int buf, int t) {
        const int k0 = t << 6;
#pragma unroll
        for (int j = 0; j < 8; ++j) {
            int s = wid * 8 + j;
            if (s < 16) {
                int r = s * 8 + rl;
                int cs = ch ^ (r & 7);
                GLDS16(A + (long)(bm + r) * lda + k0 + cs * 8, &As[buf][s * 8][0]);
            } else {
                int r = (s - 16) * 8 + rl;
                int cs = ch ^ (r & 7);
                GLDS16(Bt + (long)(bn + r) * K + k0 + cs * 8, &Bs[buf][(s - 16) * 8][0]);
            }
        }
    };

    f32x4 acc[4][4] = {};

    STAGE(0, 0);
    STAGE(1, 1);
    for (int t = 0; t < nt; ++t) {
        const int buf = t & 1;
        if (t + 1 < nt) { asm volatile("s_waitcnt vmcnt(8)" ::: "memory"); }
        else            { asm volatile("s_waitcnt vmcnt(0)" ::: "memory"); }
        asm volatile("s_barrier" ::: "memory");
        s16x8 avA[2][4], avB[2][4];
        const int sw = l15 & 7;
#pragma unroll
        for (int kk = 0; kk < 2; ++kk) {
#pragma unroll
            for (int m = 0; m < 4; ++m)
                avA[kk][m] = *(const s16x8*)&As[buf][wr * 64 + m * 16 + l15][(((kk << 2) | l4) ^ sw) << 3];
#pragma unroll
            for (int n = 0; n < 4; ++n)
                avB[kk][n] = *(const s16x8*)&Bs[buf][wc * 64 + n * 16 + l15][(((kk << 2) | l4) ^ sw) << 3];
        }
        asm volatile("s_waitcnt lgkmcnt(0)" ::: "memory");
        asm volatile("s_barrier" ::: "memory");
        if (t + 2 < nt) STAGE(buf, t + 2);
#pragma unroll
        for (int kk = 0; kk < 2; ++kk)
#pragma unroll
            for (int m = 0; m < 4; ++m)
#pragma unroll
                for (int n = 0; n < 4; ++n)
                    acc[m][n] = __builtin_amdgcn_mfma_f32_16x16x32_bf16(avA[kk][m], avB[kk][n], acc[m][n], 0, 0, 0);
    }

#pragma unroll
    for (int m = 0; m < 4; ++m) {
        int row0 = bm + wr * 64 + m * 16 + l4 * 4;
#pragma unroll
        for (int n = 0; n < 4; ++n) {
            int col = bn + wc * 64 + n * 16 + l15;
            float bv = bias[col];
#pragma unroll
            for (int j = 0; j < 4; ++j) {
                float v = acc[m][n][j] + bv;
                if (ACT == 1) { if (col < eluCut) v = (v > 0.f) ? v + 1.f : __expf(v); }
                else if (ACT == 2) v = fmaxf(v, 0.f);
                Cb[(long)(row0 + j) * ldc + col] = f2bf(v);
            }
        }
    }
}

// ---- fused GEMM + bias + act + residual + LayerNorm (BM=32, 8 waves) — R8 version ----
template<int ACT>
__global__ __launch_bounds__(512, 4) void gemmln_kernel(
    const short* __restrict__ A, const short* __restrict__ Bt,
    const float* __restrict__ bias,
    const float* __restrict__ gam, const float* __restrict__ bet,
    const float* __restrict__ Fin, float* __restrict__ Fout,
    short* __restrict__ xb, int K, int lda)
{
    __shared__ short As[2][32][64];
    __shared__ short Bs[2][256][64];
    __shared__ float partS[8][32];
    __shared__ float partQ[8][32];
    __shared__ float muA[32];
    __shared__ float rsA[32];
    const int tid = threadIdx.x;
    const int lane = tid & 63;
    const int w = tid >> 6;
    const int bm = blockIdx.x * 32;
    const int l15 = lane & 15, l4 = lane >> 4;
    const int nt = K >> 6;
    const int rl = lane >> 3;
    const int ch = lane & 7;

    auto STAGE = [&](int buf, int t) {
        const int k0 = t << 6;
#pragma unroll
        for (int j = 0; j < 5; ++j) {
            int s = w + j * 8;
            if (s < 36) {
                if (s < 4) {
                    int r = s * 8 + rl;
                    int cs = ch ^ (r & 7);
                    GLDS16(A + (long)(bm + r) * lda + k0 + cs * 8, &As[buf][s * 8][0]);
                } else {
                    int r = (s - 4) * 8 + rl;
                    int cs = ch ^ (r & 7);
                    GLDS16(Bt + (long)r * K + k0 + cs * 8, &Bs[buf][(s - 4) * 8][0]);
                }
            }
        }
    };

    f32x4 acc[2][2] = {};

    STAGE(0, 0);
    STAGE(1, 1);
    for (int t = 0; t < nt; ++t) {
        const int buf = t & 1;
        if (t + 1 < nt) {
            if (w < 4) { asm volatile("s_waitcnt vmcnt(5)" ::: "memory"); }
            else       { asm volatile("s_waitcnt vmcnt(4)" ::: "memory"); }
        } else {
            asm volatile("s_waitcnt vmcnt(0)" ::: "memory");
        }
        asm volatile("s_barrier" ::: "memory");
        s16x8 avA[2][2], avB[2][2];
        const int sw = l15 & 7;
#pragma unroll
        for (int kk = 0; kk < 2; ++kk) {
#pragma unroll
            for (int m = 0; m < 2; ++m)
                avA[kk][m] = *(const s16x8*)&As[buf][m * 16 + l15][(((kk << 2) | l4) ^ sw) << 3];
#pragma unroll
            for (int n = 0; n < 2; ++n)
                avB[kk][n] = *(const s16x8*)&Bs[buf][w * 32 + n * 16 + l15][(((kk << 2) | l4) ^ sw) << 3];
        }
        asm volatile("s_waitcnt lgkmcnt(0)" ::: "memory");
        asm volatile("s_barrier" ::: "memory");
        if (t + 2 < nt) STAGE(buf, t + 2);
#pragma unroll
        for (int kk = 0; kk < 2; ++kk)
#pragma unroll
            for (int m = 0; m < 2; ++m)
#pragma unroll
                for (int n = 0; n < 2; ++n)
                    acc[m][n] = __builtin_amdgcn_mfma_f32_16x16x32_bf16(avA[kk][m], avB[kk][n], acc[m][n], 0, 0, 0);
    }

#pragma unroll
    for (int m = 0; m < 2; ++m) {
#pragma unroll
        for (int n = 0; n < 2; ++n) {
            int col = w * 32 + n * 16 + l15;
            float bv = bias[col];
#pragma unroll
            for (int j = 0; j < 4; ++j) {
                int r = m * 16 + l4 * 4 + j;
                float v = acc[m][n][j] + bv;
                if (ACT == 2) v = fmaxf(v, 0.f);
                v += Fin[(long)(bm + r) * DIM + col];
                acc[m][n][j] = v;
            }
        }
    }
#pragma unroll
    for (int m = 0; m < 2; ++m)
#pragma unroll
        for (int j = 0; j < 4; ++j) {
            float s = acc[m][0][j] + acc[m][1][j];
            float q = acc[m][0][j] * acc[m][0][j] + acc[m][1][j] * acc[m][1][j];
#pragma unroll
            for (int off = 1; off < 16; off <<= 1) {
                s += __shfl_xor(s, off);
                q += __shfl_xor(q, off);
            }
            if (l15 == 0) {
                partS[w][m * 16 + l4 * 4 + j] = s;
                partQ[w][m * 16 + l4 * 4 + j] = q;
            }
        }
    __syncthreads();
    if (tid < 32) {
        float S = 0, Qq = 0;
#pragma unroll
        for (int ww = 0; ww < 8; ++ww) { S += partS[ww][tid]; Qq += partQ[ww][tid]; }
        float mu = S * (1.f / 256.f);
        float var = Qq * (1.f / 256.f) - mu * mu;
        muA[tid] = mu;
        rsA[tid] = rsqrtf(var + 1e-3f);
    }
    __syncthreads();
#pragma unroll
    for (int m = 0; m < 2; ++m)
#pragma unroll
        for (int j = 0; j < 4; ++j) {
            int r = m * 16 + l4 * 4 + j;
            float mu = muA[r], rs = rsA[r];
#pragma unroll
            for (int n = 0; n < 2; ++n) {
                int col = w * 32 + n * 16 + l15;
                float t = (acc[m][n][j] - mu) * rs * gam[col] + bet[col];
                long o = (long)(bm + r) * DIM + col;
                xb[o] = f2bf(t);
                Fout[o] = t;
            }
        }
}

// ---- fused Q-projection + linear attention (per-head denominator — FIXED) ----
// Phase 1: Qf = elu(x @ WqT^T + bq)+1 (128x256 tile, 8 waves 2x4).
// Phase 1.5: PER-HEAD den partials (head h cols = h*32..h*32+31, entirely within
// one wc group: n in {0,1} -> head 2wc, n in {2,3} -> head 2wc+1) + Qf -> swizzled LDS.
// Phase 2: wave w = head w: out^T = KVT_h @ Qf_h^T (16 MFMAs), x 1/den[h][r], store.
__global__ __launch_bounds__(512, 1) void qattn_kernel(
    const short* __restrict__ A, const short* __restrict__ Bt,
    const float* __restrict__ bias, const float* __restrict__ kv,
    const float* __restrict__ ksum, short* __restrict__ outp)
{
    __shared__ char smem[98304 + 24576 + 1024 + 4096];
    short (*As)[128][64] = (short(*)[128][64])(smem);
    short (*Bs)[256][64] = (short(*)[256][64])(smem + 32768);
    short (*QfL)[256] = (short(*)[256])(smem);                    // overlaps As + Bs[0]
    short (*kvbT)[32][48] = (short(*)[32][48])(smem + 98304);     // [h][c][d], row pad->48
    float* ksumAll = (float*)(smem + 98304 + 24576);
    float (*partDenH)[128] = (float(*)[128])(smem + 98304 + 24576 + 1024);  // [head][row]

    const int tid = threadIdx.x;
    const int lane = tid & 63;
    const int w = tid >> 6;
    const int wr = w >> 2, wc = w & 3;
    const int bm = blockIdx.x * 128;
    const int b = bm >> 12;
    const int l15 = lane & 15, l4 = lane >> 4;
    const int rl = lane >> 3;
    const int ch = lane & 7;

    // prep: KV^T per head (kvbT[h][c][d] = kv[bh][d*32+c]) + ksumAll[h*32+d]
    for (int idx = tid; idx < 8192; idx += 512) {
        int h = idx >> 10, j = idx & 1023, d = j >> 5, m = j & 31;
        kvbT[h][m][d] = f2bf(kv[(long)(b * 8 + h) * 1024 + j]);
    }
    if (tid < 256) ksumAll[tid] = ksum[(b * 8 + (tid >> 5)) * 32 + (tid & 31)];

    auto STAGE = [&](int buf, int t) {
        const int k0 = t << 6;
#pragma unroll
        for (int j = 0; j < 6; ++j) {
            int s = w * 6 + j;
            if (s < 16) {
                int r = s * 8 + rl;
                int cs = ch ^ (r & 7);
                GLDS16(A + (long)(bm + r) * 256 + k0 + cs * 8, &As[buf][s * 8][0]);
            } else {
                int r = (s - 16) * 8 + rl;
                int cs = ch ^ (r & 7);
                GLDS16(Bt + (long)r * 256 + k0 + cs * 8, &Bs[buf][(s - 16) * 8][0]);
            }
        }
    };

    f32x4 acc[4][4] = {};

    STAGE(0, 0);
    STAGE(1, 1);
#pragma unroll
    for (int t = 0; t < 4; ++t) {
        const int buf = t & 1;
        if (t < 3) { asm volatile("s_waitcnt vmcnt(6)" ::: "memory"); }
        else       { asm volatile("s_waitcnt vmcnt(0)" ::: "memory"); }
        asm volatile("s_barrier" ::: "memory");
        s16x8 avA[2][4], avB[2][4];
        const int sw = l15 & 7;
#pragma unroll
        for (int kk = 0; kk < 2; ++kk) {
#pragma unroll
            for (int m = 0; m < 4; ++m)
                avA[kk][m] = *(const s16x8*)&As[buf][wr * 64 + m * 16 + l15][(((kk << 2) | l4) ^ sw) << 3];
#pragma unroll
            for (int n = 0; n < 4; ++n)
                avB[kk][n] = *(const s16x8*)&Bs[buf][wc * 64 + n * 16 + l15][(((kk << 2) | l4) ^ sw) << 3];
        }
        asm volatile("s_waitcnt lgkmcnt(0)" ::: "memory");
        asm volatile("s_barrier" ::: "memory");
        if (t < 2) STAGE(buf, t + 2);
#pragma unroll
        for (int kk = 0; kk < 2; ++kk)
#pragma unroll
            for (int m = 0; m < 4; ++m)
#pragma unroll
                for (int n = 0; n < 4; ++n)
                    acc[m][n] = __builtin_amdgcn_mfma_f32_16x16x32_bf16(avA[kk][m], avB[kk][n], acc[m][n], 0, 0, 0);
    }
    // after the final in-loop barrier (preceded by every wave's lgkmcnt(0)),
    // no LDS reads of As/Bs remain -> safe to overwrite with QfL.

    // phase 1.5: bias + elu+1; PER-HEAD den partials; Qf -> swizzled QfL
#pragma unroll
    for (int m = 0; m < 4; ++m)
#pragma unroll
        for (int n = 0; n < 4; ++n) {
            int col = wc * 64 + n * 16 + l15;
            float bv = bias[col];
#pragma unroll
            for (int j = 0; j < 4; ++j) {
                float v = acc[m][n][j] + bv;
                acc[m][n][j] = (v > 0.f) ? v + 1.f : __expf(v);
            }
        }
#pragma unroll
    for (int m = 0; m < 4; ++m)
#pragma unroll
        for (int j = 0; j < 4; ++j) {
            // head 2wc   <- cols wc*64 + {0..31}  (n = 0,1)
            // head 2wc+1 <- cols wc*64 + {32..63} (n = 2,3)
            float p0 = acc[m][0][j] * ksumAll[wc * 64 + l15]
                     + acc[m][1][j] * ksumAll[wc * 64 + 16 + l15];
            float p1 = acc[m][2][j] * ksumAll[wc * 64 + 32 + l15]
                     + acc[m][3][j] * ksumAll[wc * 64 + 48 + l15];
#pragma unroll
            for (int off = 1; off < 16; off <<= 1) {
                p0 += __shfl_xor(p0, off);
                p1 += __shfl_xor(p1, off);
            }
            if (l15 == 0) {
                int r = wr * 64 + m * 16 + l4 * 4 + j;
                partDenH[wc * 2 + 0][r] = p0;
                partDenH[wc * 2 + 1][r] = p1;
            }
        }
#pragma unroll
    for (int m = 0; m < 4; ++m)
#pragma unroll
        for (int n = 0; n < 4; ++n) {
            int col = wc * 64 + n * 16 + l15;
#pragma unroll
            for (int j = 0; j < 4; ++j) {
                int r = wr * 64 + m * 16 + l4 * 4 + j;
                int chunk = (col >> 3) ^ (r & 7);
                QfL[r][chunk * 8 + (col & 7)] = f2bf(acc[m][n][j]);
            }
        }
    __syncthreads();

    // phase 2: wave w handles head h=w. out^T = KVT_h @ Qf_h^T, x 1/den[h][r].
    {
        const int h = w;
        s16x8 afr[2];
#pragma unroll
        for (int ct = 0; ct < 2; ++ct)
            afr[ct] = *(const s16x8*)&kvbT[h][ct * 16 + l15][l4 * 8];
#pragma unroll
        for (int rt = 0; rt < 8; ++rt) {
            int r = rt * 16 + l15;
            int chunk = (h * 4 + l4) ^ (r & 7);
            s16x8 bfr = *(const s16x8*)&QfL[r][chunk * 8];
            float z = 1.f / (partDenH[h][r] + 1e-6f);
#pragma unroll
            for (int ct = 0; ct < 2; ++ct) {
                f32x4 zero = {0.f, 0.f, 0.f, 0.f};
                f32x4 po = __builtin_amdgcn_mfma_f32_16x16x32_bf16(afr[ct], bfr, zero, 0, 0, 0);
                s16x4 o4;
#pragma unroll
                for (int j = 0; j < 4; ++j) o4[j] = f2bf(po[j] * z);
                *(s16x4*)&outp[(long)(bm + r) * 512 + h * 32 + ct * 16 + l4 * 4] = o4;
            }
        }
    }
}

// ---------------- KV partial reduce ----------------
__global__ __launch_bounds__(256) void kvpart_kernel(
    const short* __restrict__ KV, float* __restrict__ part)
{
    __shared__ float kfs[32][32];
    __shared__ float vsh[32][32];
    int c = blockIdx.x, bh = blockIdx.y;
    int b = bh >> 3, h = bh & 7;
    int tid = threadIdx.x;
    int d = tid >> 3, m0 = (tid & 7) * 4;
    float acc0 = 0, acc1 = 0, acc2 = 0, acc3 = 0, ks = 0;
    long rowBase = ((long)b * SEQ + c * 512) * 512 + h * DH;
    int lrow = (tid & 127) >> 2, cg = tid & 3;
    for (int s0 = 0; s0 < 512; s0 += 32) {
        long rb = rowBase + (long)(s0 + lrow) * 512 + cg * 8 + ((tid < 128) ? 0 : 256);
        s16x8 v8 = *(const s16x8*)(KV + rb);
        float* dst = (tid < 128) ? &kfs[lrow][cg * 8] : &vsh[lrow][cg * 8];
#pragma unroll
        for (int e = 0; e < 8; ++e) dst[e] = bf2f(v8[e]);
        __syncthreads();
#pragma unroll
        for (int s = 0; s < 32; ++s) {
            float kd = kfs[s][d];
            acc0 += kd * vsh[s][m0];
            acc1 += kd * vsh[s][m0 + 1];
            acc2 += kd * vsh[s][m0 + 2];
            acc3 += kd * vsh[s][m0 + 3];
        }
        if (tid < 32) {
#pragma unroll
            for (int s = 0; s < 32; ++s) ks += kfs[s][tid];
        }
        __syncthreads();
    }
    float* pb = part + ((long)bh * NCHUNK + c) * 1056;
    pb[tid * 4 + 0] = acc0; pb[tid * 4 + 1] = acc1;
    pb[tid * 4 + 2] = acc2; pb[tid * 4 + 3] = acc3;
    if (tid < 32) pb[1024 + tid] = ks;
}

__global__ __launch_bounds__(256) void kvred_kernel(
    const float* __restrict__ part, float* __restrict__ kv, float* __restrict__ ksum)
{
    int bh = blockIdx.x, tid = threadIdx.x;
    const float* pb = part + (long)bh * NCHUNK * 1056;
    float s0 = 0, s1 = 0, s2 = 0, s3 = 0;
    for (int cc = 0; cc < NCHUNK; ++cc) {
        const float* p = pb + cc * 1056 + tid * 4;
        s0 += p[0]; s1 += p[1]; s2 += p[2]; s3 += p[3];
    }
    float* kb = kv + (long)bh * 1024 + tid * 4;
    kb[0] = s0; kb[1] = s1; kb[2] = s2; kb[3] = s3;
    if (tid < 32) {
        float ss = 0;
        for (int cc = 0; cc < NCHUNK; ++cc) ss += pb[cc * 1056 + 1024 + tid];
        ksum[bh * 32 + tid] = ss;
    }
}

// =======================================================================================
extern "C" void kernel_launch(void* const* d_in, const int* in_sizes, int n_in,
                              void* d_out, int out_size, void* d_ws, size_t ws_size,
                              hipStream_t stream)
{
    const float* Qin = (const float*)d_in[0];
    const float* Kin = (const float*)d_in[1];
    const float* Wq1 = (const float*)d_in[2];
    const float* Wk1 = (const float*)d_in[3];
    const float* Wv1 = (const float*)d_in[4];
    const float* Wo1 = (const float*)d_in[5];
    const float* bq1 = (const float*)d_in[6];
    const float* bk1 = (const float*)d_in[7];
    const float* bv1 = (const float*)d_in[8];
    const float* bo1 = (const float*)d_in[9];
    const float* Wq2 = (const float*)d_in[10];
    const float* Wk2 = (const float*)d_in[11];
    const float* Wv2 = (const float*)d_in[12];
    const float* Wo2 = (const float*)d_in[13];
    const float* bq2 = (const float*)d_in[14];
    const float* bk2 = (const float*)d_in[15];
    const float* bv2 = (const float*)d_in[16];
    const float* bo2 = (const float*)d_in[17];
    const float* Wf1 = (const float*)d_in[18];
    const float* bf1 = (const float*)d_in[19];
    const float* Wf2 = (const float*)d_in[20];
    const float* bf2 = (const float*)d_in[21];
    const float* ln1g = (const float*)d_in[22];
    const float* ln1b = (const float*)d_in[23];
    const float* ln2g = (const float*)d_in[24];
    const float* ln2b = (const float*)d_in[25];
    const float* ln3g = (const float*)d_in[26];
    const float* ln3b = (const float*)d_in[27];
    (void)in_sizes; (void)n_in; (void)out_size;

    const size_t NEED = 117841920ULL;   // round-2-proven guard
    if (ws_size < NEED) return;

    char* ws = (char*)d_ws;
    size_t off = 0;
    auto alloc = [&](size_t bytes) -> void* {
        void* p = ws + off;
        off = (off + bytes + 255) & ~(size_t)255;
        return p;
    };
    const size_t ACT_E = (size_t)M_TOTAL * DIM;

    short* wkv1t = (short*)alloc((size_t)NL * 512 * 256 * 2);
    short* wkv2t = (short*)alloc((size_t)NL * 512 * 256 * 2);
    short* wq1t  = (short*)alloc((size_t)NL * 65536 * 2);
    short* wo1t  = (short*)alloc((size_t)NL * 65536 * 2);
    short* wq2t  = (short*)alloc((size_t)NL * 65536 * 2);
    short* wo2t  = (short*)alloc((size_t)NL * 65536 * 2);
    short* wf1t  = (short*)alloc((size_t)NL * 262144 * 2);
    short* wf2t  = (short*)alloc((size_t)NL * 262144 * 2);
    float* bkv1  = (float*)alloc((size_t)NL * 512 * 4);
    float* bkv2  = (float*)alloc((size_t)NL * 512 * 4);
    short* kbf = (short*)alloc(ACT_E * 2);
    short* A0  = (short*)alloc(ACT_E * 2);          // bf16 trunk mirror (GEMM inputs)
    short* BIG = (short*)alloc((size_t)M_TOTAL * 512 * 2);
    float* Fx  = (float*)alloc(ACT_E * 4);          // fp32 residual trunk
    float* part = (float*)alloc((size_t)64 * NCHUNK * 1056 * 4);
    float* kvb  = (float*)alloc((size_t)64 * 1024 * 4);
    float* ksb  = (float*)alloc((size_t)64 * 32 * 4);

    peadd_kernel<<<2048, 256, 0, stream>>>(Qin, A0, Fx, (int)ACT_E);
    kconv_kernel<<<2048, 256, 0, stream>>>(Kin, kbf, (int)ACT_E);
    wtrans_kernel<<<dim3(8, 8, NL), dim3(32, 8), 0, stream>>>(Wk1, wkv1t, 256, 256, 512 * 256, 0);
    wtrans_kernel<<<dim3(8, 8, NL), dim3(32, 8), 0, stream>>>(Wv1, wkv1t, 256, 256, 512 * 256, 256);
    wtrans_kernel<<<dim3(8, 8, NL), dim3(32, 8), 0, stream>>>(Wk2, wkv2t, 256, 256, 512 * 256, 0);
    wtrans_kernel<<<dim3(8, 8, NL), dim3(32, 8), 0, stream>>>(Wv2, wkv2t, 256, 256, 512 * 256, 256);
    wtrans_kernel<<<dim3(8, 8, NL), dim3(32, 8), 0, stream>>>(Wq1, wq1t, 256, 256, 65536, 0);
    wtrans_kernel<<<dim3(8, 8, NL), dim3(32, 8), 0, stream>>>(Wo1, wo1t, 256, 256, 65536, 0);
    wtrans_kernel<<<dim3(8, 8, NL), dim3(32, 8), 0, stream>>>(Wq2, wq2t, 256, 256, 65536, 0);
    wtrans_kernel<<<dim3(8, 8, NL), dim3(32, 8), 0, stream>>>(Wo2, wo2t, 256, 256, 65536, 0);
    wtrans_kernel<<<dim3(8, 32, NL), dim3(32, 8), 0, stream>>>(Wf1, wf1t, 256, 1024, 262144, 0);
    wtrans_kernel<<<dim3(32, 8, NL), dim3(32, 8), 0, stream>>>(Wf2, wf2t, 1024, 256, 262144, 0);
    bpack_kernel<<<NL, 512, 0, stream>>>(bk1, bv1, bk2, bv2, bkv1, bkv2);

    dim3 blk(256), blk512(512);

    for (int i = 0; i < NL; ++i) {
        const short* wkv1i = wkv1t + (size_t)i * 512 * 256;
        const short* wkv2i = wkv2t + (size_t)i * 512 * 256;
        const short* wq1i = wq1t + (size_t)i * 65536;
        const short* wo1i = wo1t + (size_t)i * 65536;
        const short* wq2i = wq2t + (size_t)i * 65536;
        const short* wo2i = wo2t + (size_t)i * 65536;
        const short* wf1i = wf1t + (size_t)i * 262144;
        const short* wf2i = wf2t + (size_t)i * 262144;

        // ---- self linear-attention (x1 -> x2)
        gemm_bt_kernel<1><<<dim3(256, 4), blk, 0, stream>>>(A0, wkv1i, bkv1 + i * 512, BIG, 512, 256, 256, 512, 256);
        kvpart_kernel<<<dim3(NCHUNK, 64), blk, 0, stream>>>(BIG, part);
        kvred_kernel<<<64, blk, 0, stream>>>(part, kvb, ksb);
        qattn_kernel<<<M_TOTAL / 128, blk512, 0, stream>>>(A0, wq1i, bq1 + i * 256, kvb, ksb, BIG + 256);
        gemmln_kernel<0><<<M_TOTAL / 32, blk512, 0, stream>>>(BIG + 256, wo1i, bo1 + i * 256,
            ln1g + i * 256, ln1b + i * 256, Fx, Fx, A0, 256, 512);

        // ---- cross linear-attention (x2, K -> x3)
        gemm_bt_kernel<1><<<dim3(256, 4), blk, 0, stream>>>(kbf, wkv2i, bkv2 + i * 512, BIG, 512, 256, 256, 512, 256);
        kvpart_kernel<<<dim3(NCHUNK, 64), blk, 0, stream>>>(BIG, part);
        kvred_kernel<<<64, blk, 0, stream>>>(part, kvb, ksb);
        qattn_kernel<<<M_TOTAL / 128, blk512, 0, stream>>>(A0, wq2i, bq2 + i * 256, kvb, ksb, BIG + 256);
        gemmln_kernel<0><<<M_TOTAL / 32, blk512, 0, stream>>>(BIG + 256, wo2i, bo2 + i * 256,
            ln2g + i * 256, ln2b + i * 256, Fx, Fx, A0, 256, 512);

        // ---- FFN (x3 -> x1'), 2 chunks; hidden in BIG
        for (int c = 0; c < 2; ++c) {
            const size_t ro = (size_t)c * FFN_ROWS * DIM;
            gemm_bt_kernel<2><<<dim3(FFN_ROWS / 128, 8), blk, 0, stream>>>(
                A0 + ro, wf1i, bf1 + i * 1024, BIG, 1024, 256, 256, 1024, 0);
            float* foutC = ((i == NL - 1) ? (float*)d_out : Fx) + ro;
            gemmln_kernel<2><<<FFN_ROWS / 32, blk512, 0, stream>>>(BIG, wf2i, bf2 + i * 256,
                ln3g + i * 256, ln3b + i * 256, Fx + ro, foutC, A0 + ro, 1024, 1024);
        }
    }
}

// Round 11
// 1535.181 us; speedup vs baseline: 1.3817x; 1.0253x over previous
//
#include <hip/hip_runtime.h>

#define BATCH 8
#define SEQ 4096
#define DIM 256
#define NH 8
#define DH 32
#define FFN_DIM 1024
#define NL 6
#define M_TOTAL (BATCH * SEQ)   // 32768
#define NCHUNK 8
#define FFN_ROWS 16384

typedef __attribute__((ext_vector_type(8))) short s16x8;
typedef __attribute__((ext_vector_type(4))) short s16x4;
typedef __attribute__((ext_vector_type(4))) float f32x4;

__device__ __forceinline__ float bf2f(short s) {
    union { unsigned u; float f; } x;
    x.u = ((unsigned)(unsigned short)s) << 16;
    return x.f;
}
__device__ __forceinline__ short f2bf(float f) {
    union { float f; unsigned u; } x;
    x.f = f;
    unsigned r = x.u + 0x7fffu + ((x.u >> 16) & 1u);
    return (short)(r >> 16);
}

#define GLDS16(gp, sp) __builtin_amdgcn_global_load_lds( \
    (const __attribute__((address_space(1))) void*)(gp), \
    (__attribute__((address_space(3))) void*)(sp), 16, 0, 0)

// ---------------- positional encoding add -> bf16 trunk ----------------
__global__ void peadd_kernel(const float* __restrict__ Q, short* __restrict__ xb, int total)
{
    const float c = 9.210340371976184f / 256.f;  // ln(1e4)/256
    for (int idx = blockIdx.x * 256 + threadIdx.x; idx < total; idx += gridDim.x * 256) {
        int d = idx & (DIM - 1);
        int l = (idx >> 8) & (SEQ - 1);
        float rate = __expf(-(float)(d & ~1) * c);
        float ang = (float)l * rate;
        float pe = (d & 1) ? cosf(ang) : sinf(ang);
        xb[idx] = f2bf(Q[idx] + pe);
    }
}

__global__ void kconv_kernel(const float* __restrict__ src, short* __restrict__ dst, int total)
{
    for (int idx = blockIdx.x * 256 + threadIdx.x; idx < total; idx += gridDim.x * 256)
        dst[idx] = f2bf(src[idx]);
}

// ---- weight transpose+convert: Wt[lstride*z + (rowoff+n)*K + k] = W[z][k][n] ----
__global__ void wtrans_kernel(const float* __restrict__ W, short* __restrict__ Wt,
                              int K, int N, int lstride, int rowoff)
{
    __shared__ float tile[32][33];
    int k0 = blockIdx.x * 32, n0 = blockIdx.y * 32;
    const float* Wl = W + (long)blockIdx.z * K * N;
    short* Wtl = Wt + (long)blockIdx.z * lstride;
    int tx = threadIdx.x, ty = threadIdx.y;
#pragma unroll
    for (int r = 0; r < 4; ++r)
        tile[ty + r * 8][tx] = Wl[(long)(k0 + ty + r * 8) * N + n0 + tx];
    __syncthreads();
#pragma unroll
    for (int r = 0; r < 4; ++r)
        Wtl[(long)(rowoff + n0 + ty + r * 8) * K + k0 + tx] = f2bf(tile[tx][ty + r * 8]);
}

// ---- bias pack ----
__global__ void bpack_kernel(const float* __restrict__ bk1, const float* __restrict__ bv1,
                             const float* __restrict__ bk2, const float* __restrict__ bv2,
                             float* __restrict__ o1, float* __restrict__ o2)
{
    int z = blockIdx.x, t = threadIdx.x;
    o1[z * 512 + t] = (t < 256) ? bk1[z * 256 + t] : bv1[z * 256 + t - 256];
    o2[z * 512 + t] = (t < 256) ? bk2[z * 256 + t] : bv2[z * 256 + t - 256];
}

// ---------------- bf16 MFMA GEMM (coalesced+swizzled staging, R8-proven) -------------
template<int ACT>
__global__ __launch_bounds__(256, 2) void gemm_bt_kernel(
    const short* __restrict__ A, const short* __restrict__ Bt,
    const float* __restrict__ bias, short* __restrict__ Cb,
    int N, int K, int lda, int ldc, int eluCut)
{
    __shared__ short As[2][128][64];
    __shared__ short Bs[2][128][64];
    const int tid = threadIdx.x;
    const int lane = tid & 63;
    const int wid = tid >> 6;
    const int wr = wid >> 1, wc = wid & 1;
    const int bm = blockIdx.x * 128, bn = blockIdx.y * 128;
    const int l15 = lane & 15, l4 = lane >> 4;
    const int rl = lane >> 3;
    const int ch = lane & 7;
    const int nt = K >> 6;

    auto STAGE = [&](int buf, int t) {
        const int k0 = t << 6;
#pragma unroll
        for (int j = 0; j < 8; ++j) {
            int s = wid * 8 + j;
            if (s < 16) {
                int r = s * 8 + rl;
                int cs = ch ^ (r & 7);
                GLDS16(A + (long)(bm + r) * lda + k0 + cs * 8, &As[buf][s * 8][0]);
            } else {
                int r = (s - 16) * 8 + rl;
                int cs = ch ^ (r & 7);
                GLDS16(Bt + (long)(bn + r) * K + k0 + cs * 8, &Bs[buf][(s - 16) * 8][0]);
            }
        }
    };

    f32x4 acc[4][4] = {};

    STAGE(0, 0);
    STAGE(1, 1);
    for (int t = 0; t < nt; ++t) {
        const int buf = t & 1;
        if (t + 1 < nt) { asm volatile("s_waitcnt vmcnt(8)" ::: "memory"); }
        else            { asm volatile("s_waitcnt vmcnt(0)" ::: "memory"); }
        asm volatile("s_barrier" ::: "memory");
        s16x8 avA[2][4], avB[2][4];
        const int sw = l15 & 7;
#pragma unroll
        for (int kk = 0; kk < 2; ++kk) {
#pragma unroll
            for (int m = 0; m < 4; ++m)
                avA[kk][m] = *(const s16x8*)&As[buf][wr * 64 + m * 16 + l15][(((kk << 2) | l4) ^ sw) << 3];
#pragma unroll
            for (int n = 0; n < 4; ++n)
                avB[kk][n] = *(const s16x8*)&Bs[buf][wc * 64 + n * 16 + l15][(((kk << 2) | l4) ^ sw) << 3];
        }
        asm volatile("s_waitcnt lgkmcnt(0)" ::: "memory");
        asm volatile("s_barrier" ::: "memory");
        if (t + 2 < nt) STAGE(buf, t + 2);
#pragma unroll
        for (int kk = 0; kk < 2; ++kk)
#pragma unroll
            for (int m = 0; m < 4; ++m)
#pragma unroll
                for (int n = 0; n < 4; ++n)
                    acc[m][n] = __builtin_amdgcn_mfma_f32_16x16x32_bf16(avA[kk][m], avB[kk][n], acc[m][n], 0, 0, 0);
    }

#pragma unroll
    for (int m = 0; m < 4; ++m) {
        int row0 = bm + wr * 64 + m * 16 + l4 * 4;
#pragma unroll
        for (int n = 0; n < 4; ++n) {
            int col = bn + wc * 64 + n * 16 + l15;
            float bv = bias[col];
#pragma unroll
            for (int j = 0; j < 4; ++j) {
                float v = acc[m][n][j] + bv;
                if (ACT == 1) { if (col < eluCut) v = (v > 0.f) ? v + 1.f : __expf(v); }
                else if (ACT == 2) v = fmaxf(v, 0.f);
                Cb[(long)(row0 + j) * ldc + col] = f2bf(v);
            }
        }
    }
}

// ---- fused GEMM + bias + act + bf16-residual + LayerNorm (BM=32, 8 waves) ----
// Fin = bf16 trunk (== previous LN output). Fout (fp32) written only if non-null.
template<int ACT>
__global__ __launch_bounds__(512, 4) void gemmln_kernel(
    const short* __restrict__ A, const short* __restrict__ Bt,
    const float* __restrict__ bias,
    const float* __restrict__ gam, const float* __restrict__ bet,
    const short* __restrict__ Fin, float* __restrict__ Fout,
    short* __restrict__ xb, int K, int lda)
{
    __shared__ short As[2][32][64];
    __shared__ short Bs[2][256][64];
    __shared__ float partS[8][32];
    __shared__ float partQ[8][32];
    __shared__ float muA[32];
    __shared__ float rsA[32];
    const int tid = threadIdx.x;
    const int lane = tid & 63;
    const int w = tid >> 6;
    const int bm = blockIdx.x * 32;
    const int l15 = lane & 15, l4 = lane >> 4;
    const int nt = K >> 6;
    const int rl = lane >> 3;
    const int ch = lane & 7;

    auto STAGE = [&](int buf, int t) {
        const int k0 = t << 6;
#pragma unroll
        for (int j = 0; j < 5; ++j) {
            int s = w + j * 8;
            if (s < 36) {
                if (s < 4) {
                    int r = s * 8 + rl;
                    int cs = ch ^ (r & 7);
                    GLDS16(A + (long)(bm + r) * lda + k0 + cs * 8, &As[buf][s * 8][0]);
                } else {
                    int r = (s - 4) * 8 + rl;
                    int cs = ch ^ (r & 7);
                    GLDS16(Bt + (long)r * K + k0 + cs * 8, &Bs[buf][(s - 4) * 8][0]);
                }
            }
        }
    };

    f32x4 acc[2][2] = {};

    STAGE(0, 0);
    STAGE(1, 1);
    for (int t = 0; t < nt; ++t) {
        const int buf = t & 1;
        if (t + 1 < nt) {
            if (w < 4) { asm volatile("s_waitcnt vmcnt(5)" ::: "memory"); }
            else       { asm volatile("s_waitcnt vmcnt(4)" ::: "memory"); }
        } else {
            asm volatile("s_waitcnt vmcnt(0)" ::: "memory");
        }
        asm volatile("s_barrier" ::: "memory");
        s16x8 avA[2][2], avB[2][2];
        const int sw = l15 & 7;
#pragma unroll
        for (int kk = 0; kk < 2; ++kk) {
#pragma unroll
            for (int m = 0; m < 2; ++m)
                avA[kk][m] = *(const s16x8*)&As[buf][m * 16 + l15][(((kk << 2) | l4) ^ sw) << 3];
#pragma unroll
            for (int n = 0; n < 2; ++n)
                avB[kk][n] = *(const s16x8*)&Bs[buf][w * 32 + n * 16 + l15][(((kk << 2) | l4) ^ sw) << 3];
        }
        asm volatile("s_waitcnt lgkmcnt(0)" ::: "memory");
        asm volatile("s_barrier" ::: "memory");
        if (t + 2 < nt) STAGE(buf, t + 2);
#pragma unroll
        for (int kk = 0; kk < 2; ++kk)
#pragma unroll
            for (int m = 0; m < 2; ++m)
#pragma unroll
                for (int n = 0; n < 2; ++n)
                    acc[m][n] = __builtin_amdgcn_mfma_f32_16x16x32_bf16(avA[kk][m], avB[kk][n], acc[m][n], 0, 0, 0);
    }

#pragma unroll
    for (int m = 0; m < 2; ++m) {
#pragma unroll
        for (int n = 0; n < 2; ++n) {
            int col = w * 32 + n * 16 + l15;
            float bv = bias[col];
#pragma unroll
            for (int j = 0; j < 4; ++j) {
                int r = m * 16 + l4 * 4 + j;
                float v = acc[m][n][j] + bv;
                if (ACT == 2) v = fmaxf(v, 0.f);
                v += bf2f(Fin[(long)(bm + r) * DIM + col]);
                acc[m][n][j] = v;
            }
        }
    }
#pragma unroll
    for (int m = 0; m < 2; ++m)
#pragma unroll
        for (int j = 0; j < 4; ++j) {
            float s = acc[m][0][j] + acc[m][1][j];
            float q = acc[m][0][j] * acc[m][0][j] + acc[m][1][j] * acc[m][1][j];
#pragma unroll
            for (int off = 1; off < 16; off <<= 1) {
                s += __shfl_xor(s, off);
                q += __shfl_xor(q, off);
            }
            if (l15 == 0) {
                partS[w][m * 16 + l4 * 4 + j] = s;
                partQ[w][m * 16 + l4 * 4 + j] = q;
            }
        }
    __syncthreads();
    if (tid < 32) {
        float S = 0, Qq = 0;
#pragma unroll
        for (int ww = 0; ww < 8; ++ww) { S += partS[ww][tid]; Qq += partQ[ww][tid]; }
        float mu = S * (1.f / 256.f);
        float var = Qq * (1.f / 256.f) - mu * mu;
        muA[tid] = mu;
        rsA[tid] = rsqrtf(var + 1e-3f);
    }
    __syncthreads();
#pragma unroll
    for (int m = 0; m < 2; ++m)
#pragma unroll
        for (int j = 0; j < 4; ++j) {
            int r = m * 16 + l4 * 4 + j;
            float mu = muA[r], rs = rsA[r];
#pragma unroll
            for (int n = 0; n < 2; ++n) {
                int col = w * 32 + n * 16 + l15;
                float t = (acc[m][n][j] - mu) * rs * gam[col] + bet[col];
                long o = (long)(bm + r) * DIM + col;
                xb[o] = f2bf(t);
                if (Fout) Fout[o] = t;
            }
        }
}

// ---- fused Q-projection + linear attention (per-head denominator, R10-proven) ----
__global__ __launch_bounds__(512, 1) void qattn_kernel(
    const short* __restrict__ A, const short* __restrict__ Bt,
    const float* __restrict__ bias, const float* __restrict__ kv,
    const float* __restrict__ ksum, short* __restrict__ outp)
{
    __shared__ char smem[98304 + 24576 + 1024 + 4096];
    short (*As)[128][64] = (short(*)[128][64])(smem);
    short (*Bs)[256][64] = (short(*)[256][64])(smem + 32768);
    short (*QfL)[256] = (short(*)[256])(smem);                    // overlaps As + Bs[0]
    short (*kvbT)[32][48] = (short(*)[32][48])(smem + 98304);     // [h][c][d], row pad->48
    float* ksumAll = (float*)(smem + 98304 + 24576);
    float (*partDenH)[128] = (float(*)[128])(smem + 98304 + 24576 + 1024);  // [head][row]

    const int tid = threadIdx.x;
    const int lane = tid & 63;
    const int w = tid >> 6;
    const int wr = w >> 2, wc = w & 3;
    const int bm = blockIdx.x * 128;
    const int b = bm >> 12;
    const int l15 = lane & 15, l4 = lane >> 4;
    const int rl = lane >> 3;
    const int ch = lane & 7;

    for (int idx = tid; idx < 8192; idx += 512) {
        int h = idx >> 10, j = idx & 1023, d = j >> 5, m = j & 31;
        kvbT[h][m][d] = f2bf(kv[(long)(b * 8 + h) * 1024 + j]);
    }
    if (tid < 256) ksumAll[tid] = ksum[(b * 8 + (tid >> 5)) * 32 + (tid & 31)];

    auto STAGE = [&](int buf, int t) {
        const int k0 = t << 6;
#pragma unroll
        for (int j = 0; j < 6; ++j) {
            int s = w * 6 + j;
            if (s < 16) {
                int r = s * 8 + rl;
                int cs = ch ^ (r & 7);
                GLDS16(A + (long)(bm + r) * 256 + k0 + cs * 8, &As[buf][s * 8][0]);
            } else {
                int r = (s - 16) * 8 + rl;
                int cs = ch ^ (r & 7);
                GLDS16(Bt + (long)r * 256 + k0 + cs * 8, &Bs[buf][(s - 16) * 8][0]);
            }
        }
    };

    f32x4 acc[4][4] = {};

    STAGE(0, 0);
    STAGE(1, 1);
#pragma unroll
    for (int t = 0; t < 4; ++t) {
        const int buf = t & 1;
        if (t < 3) { asm volatile("s_waitcnt vmcnt(6)" ::: "memory"); }
        else       { asm volatile("s_waitcnt vmcnt(0)" ::: "memory"); }
        asm volatile("s_barrier" ::: "memory");
        s16x8 avA[2][4], avB[2][4];
        const int sw = l15 & 7;
#pragma unroll
        for (int kk = 0; kk < 2; ++kk) {
#pragma unroll
            for (int m = 0; m < 4; ++m)
                avA[kk][m] = *(const s16x8*)&As[buf][wr * 64 + m * 16 + l15][(((kk << 2) | l4) ^ sw) << 3];
#pragma unroll
            for (int n = 0; n < 4; ++n)
                avB[kk][n] = *(const s16x8*)&Bs[buf][wc * 64 + n * 16 + l15][(((kk << 2) | l4) ^ sw) << 3];
        }
        asm volatile("s_waitcnt lgkmcnt(0)" ::: "memory");
        asm volatile("s_barrier" ::: "memory");
        if (t < 2) STAGE(buf, t + 2);
#pragma unroll
        for (int kk = 0; kk < 2; ++kk)
#pragma unroll
            for (int m = 0; m < 4; ++m)
#pragma unroll
                for (int n = 0; n < 4; ++n)
                    acc[m][n] = __builtin_amdgcn_mfma_f32_16x16x32_bf16(avA[kk][m], avB[kk][n], acc[m][n], 0, 0, 0);
    }

    // phase 1.5: bias + elu+1; PER-HEAD den partials; Qf -> swizzled QfL
#pragma unroll
    for (int m = 0; m < 4; ++m)
#pragma unroll
        for (int n = 0; n < 4; ++n) {
            int col = wc * 64 + n * 16 + l15;
            float bv = bias[col];
#pragma unroll
            for (int j = 0; j < 4; ++j) {
                float v = acc[m][n][j] + bv;
                acc[m][n][j] = (v > 0.f) ? v + 1.f : __expf(v);
            }
        }
#pragma unroll
    for (int m = 0; m < 4; ++m)
#pragma unroll
        for (int j = 0; j < 4; ++j) {
            float p0 = acc[m][0][j] * ksumAll[wc * 64 + l15]
                     + acc[m][1][j] * ksumAll[wc * 64 + 16 + l15];
            float p1 = acc[m][2][j] * ksumAll[wc * 64 + 32 + l15]
                     + acc[m][3][j] * ksumAll[wc * 64 + 48 + l15];
#pragma unroll
            for (int off = 1; off < 16; off <<= 1) {
                p0 += __shfl_xor(p0, off);
                p1 += __shfl_xor(p1, off);
            }
            if (l15 == 0) {
                int r = wr * 64 + m * 16 + l4 * 4 + j;
                partDenH[wc * 2 + 0][r] = p0;
                partDenH[wc * 2 + 1][r] = p1;
            }
        }
#pragma unroll
    for (int m = 0; m < 4; ++m)
#pragma unroll
        for (int n = 0; n < 4; ++n) {
            int col = wc * 64 + n * 16 + l15;
#pragma unroll
            for (int j = 0; j < 4; ++j) {
                int r = wr * 64 + m * 16 + l4 * 4 + j;
                int chunk = (col >> 3) ^ (r & 7);
                QfL[r][chunk * 8 + (col & 7)] = f2bf(acc[m][n][j]);
            }
        }
    __syncthreads();

    // phase 2: wave w = head w: out^T = KVT_h @ Qf_h^T, x 1/den[h][r]
    {
        const int h = w;
        s16x8 afr[2];
#pragma unroll
        for (int ct = 0; ct < 2; ++ct)
            afr[ct] = *(const s16x8*)&kvbT[h][ct * 16 + l15][l4 * 8];
#pragma unroll
        for (int rt = 0; rt < 8; ++rt) {
            int r = rt * 16 + l15;
            int chunk = (h * 4 + l4) ^ (r & 7);
            s16x8 bfr = *(const s16x8*)&QfL[r][chunk * 8];
            float z = 1.f / (partDenH[h][r] + 1e-6f);
#pragma unroll
            for (int ct = 0; ct < 2; ++ct) {
                f32x4 zero = {0.f, 0.f, 0.f, 0.f};
                f32x4 po = __builtin_amdgcn_mfma_f32_16x16x32_bf16(afr[ct], bfr, zero, 0, 0, 0);
                s16x4 o4;
#pragma unroll
                for (int j = 0; j < 4; ++j) o4[j] = f2bf(po[j] * z);
                *(s16x4*)&outp[(long)(bm + r) * 512 + h * 32 + ct * 16 + l4 * 4] = o4;
            }
        }
    }
}

// ---------------- KV partial reduce ----------------
__global__ __launch_bounds__(256) void kvpart_kernel(
    const short* __restrict__ KV, float* __restrict__ part)
{
    __shared__ float kfs[32][32];
    __shared__ float vsh[32][32];
    int c = blockIdx.x, bh = blockIdx.y;
    int b = bh >> 3, h = bh & 7;
    int tid = threadIdx.x;
    int d = tid >> 3, m0 = (tid & 7) * 4;
    float acc0 = 0, acc1 = 0, acc2 = 0, acc3 = 0, ks = 0;
    long rowBase = ((long)b * SEQ + c * 512) * 512 + h * DH;
    int lrow = (tid & 127) >> 2, cg = tid & 3;
    for (int s0 = 0; s0 < 512; s0 += 32) {
        long rb = rowBase + (long)(s0 + lrow) * 512 + cg * 8 + ((tid < 128) ? 0 : 256);
        s16x8 v8 = *(const s16x8*)(KV + rb);
        float* dst = (tid < 128) ? &kfs[lrow][cg * 8] : &vsh[lrow][cg * 8];
#pragma unroll
        for (int e = 0; e < 8; ++e) dst[e] = bf2f(v8[e]);
        __syncthreads();
#pragma unroll
        for (int s = 0; s < 32; ++s) {
            float kd = kfs[s][d];
            acc0 += kd * vsh[s][m0];
            acc1 += kd * vsh[s][m0 + 1];
            acc2 += kd * vsh[s][m0 + 2];
            acc3 += kd * vsh[s][m0 + 3];
        }
        if (tid < 32) {
#pragma unroll
            for (int s = 0; s < 32; ++s) ks += kfs[s][tid];
        }
        __syncthreads();
    }
    float* pb = part + ((long)bh * NCHUNK + c) * 1056;
    pb[tid * 4 + 0] = acc0; pb[tid * 4 + 1] = acc1;
    pb[tid * 4 + 2] = acc2; pb[tid * 4 + 3] = acc3;
    if (tid < 32) pb[1024 + tid] = ks;
}

__global__ __launch_bounds__(256) void kvred_kernel(
    const float* __restrict__ part, float* __restrict__ kv, float* __restrict__ ksum)
{
    int bh = blockIdx.x, tid = threadIdx.x;
    const float* pb = part + (long)bh * NCHUNK * 1056;
    float s0 = 0, s1 = 0, s2 = 0, s3 = 0;
    for (int cc = 0; cc < NCHUNK; ++cc) {
        const float* p = pb + cc * 1056 + tid * 4;
        s0 += p[0]; s1 += p[1]; s2 += p[2]; s3 += p[3];
    }
    float* kb = kv + (long)bh * 1024 + tid * 4;
    kb[0] = s0; kb[1] = s1; kb[2] = s2; kb[3] = s3;
    if (tid < 32) {
        float ss = 0;
        for (int cc = 0; cc < NCHUNK; ++cc) ss += pb[cc * 1056 + 1024 + tid];
        ksum[bh * 32 + tid] = ss;
    }
}

// =======================================================================================
extern "C" void kernel_launch(void* const* d_in, const int* in_sizes, int n_in,
                              void* d_out, int out_size, void* d_ws, size_t ws_size,
                              hipStream_t stream)
{
    const float* Qin = (const float*)d_in[0];
    const float* Kin = (const float*)d_in[1];
    const float* Wq1 = (const float*)d_in[2];
    const float* Wk1 = (const float*)d_in[3];
    const float* Wv1 = (const float*)d_in[4];
    const float* Wo1 = (const float*)d_in[5];
    const float* bq1 = (const float*)d_in[6];
    const float* bk1 = (const float*)d_in[7];
    const float* bv1 = (const float*)d_in[8];
    const float* bo1 = (const float*)d_in[9];
    const float* Wq2 = (const float*)d_in[10];
    const float* Wk2 = (const float*)d_in[11];
    const float* Wv2 = (const float*)d_in[12];
    const float* Wo2 = (const float*)d_in[13];
    const float* bq2 = (const float*)d_in[14];
    const float* bk2 = (const float*)d_in[15];
    const float* bv2 = (const float*)d_in[16];
    const float* bo2 = (const float*)d_in[17];
    const float* Wf1 = (const float*)d_in[18];
    const float* bf1 = (const float*)d_in[19];
    const float* Wf2 = (const float*)d_in[20];
    const float* bf2 = (const float*)d_in[21];
    const float* ln1g = (const float*)d_in[22];
    const float* ln1b = (const float*)d_in[23];
    const float* ln2g = (const float*)d_in[24];
    const float* ln2b = (const float*)d_in[25];
    const float* ln3g = (const float*)d_in[26];
    const float* ln3b = (const float*)d_in[27];
    (void)in_sizes; (void)n_in; (void)out_size;

    const size_t NEED = 117841920ULL;   // round-2-proven guard
    if (ws_size < NEED) return;

    char* ws = (char*)d_ws;
    size_t off = 0;
    auto alloc = [&](size_t bytes) -> void* {
        void* p = ws + off;
        off = (off + bytes + 255) & ~(size_t)255;
        return p;
    };
    const size_t ACT_E = (size_t)M_TOTAL * DIM;

    short* wkv1t = (short*)alloc((size_t)NL * 512 * 256 * 2);
    short* wkv2t = (short*)alloc((size_t)NL * 512 * 256 * 2);
    short* wq1t  = (short*)alloc((size_t)NL * 65536 * 2);
    short* wo1t  = (short*)alloc((size_t)NL * 65536 * 2);
    short* wq2t  = (short*)alloc((size_t)NL * 65536 * 2);
    short* wo2t  = (short*)alloc((size_t)NL * 65536 * 2);
    short* wf1t  = (short*)alloc((size_t)NL * 262144 * 2);
    short* wf2t  = (short*)alloc((size_t)NL * 262144 * 2);
    float* bkv1  = (float*)alloc((size_t)NL * 512 * 4);
    float* bkv2  = (float*)alloc((size_t)NL * 512 * 4);
    short* kbf = (short*)alloc(ACT_E * 2);
    short* A0  = (short*)alloc(ACT_E * 2);          // bf16 trunk (= residual source)
    short* BIG = (short*)alloc((size_t)M_TOTAL * 512 * 2);
    float* part = (float*)alloc((size_t)64 * NCHUNK * 1056 * 4);
    float* kvb  = (float*)alloc((size_t)64 * 1024 * 4);
    float* ksb  = (float*)alloc((size_t)64 * 32 * 4);

    peadd_kernel<<<2048, 256, 0, stream>>>(Qin, A0, (int)ACT_E);
    kconv_kernel<<<2048, 256, 0, stream>>>(Kin, kbf, (int)ACT_E);
    wtrans_kernel<<<dim3(8, 8, NL), dim3(32, 8), 0, stream>>>(Wk1, wkv1t, 256, 256, 512 * 256, 0);
    wtrans_kernel<<<dim3(8, 8, NL), dim3(32, 8), 0, stream>>>(Wv1, wkv1t, 256, 256, 512 * 256, 256);
    wtrans_kernel<<<dim3(8, 8, NL), dim3(32, 8), 0, stream>>>(Wk2, wkv2t, 256, 256, 512 * 256, 0);
    wtrans_kernel<<<dim3(8, 8, NL), dim3(32, 8), 0, stream>>>(Wv2, wkv2t, 256, 256, 512 * 256, 256);
    wtrans_kernel<<<dim3(8, 8, NL), dim3(32, 8), 0, stream>>>(Wq1, wq1t, 256, 256, 65536, 0);
    wtrans_kernel<<<dim3(8, 8, NL), dim3(32, 8), 0, stream>>>(Wo1, wo1t, 256, 256, 65536, 0);
    wtrans_kernel<<<dim3(8, 8, NL), dim3(32, 8), 0, stream>>>(Wq2, wq2t, 256, 256, 65536, 0);
    wtrans_kernel<<<dim3(8, 8, NL), dim3(32, 8), 0, stream>>>(Wo2, wo2t, 256, 256, 65536, 0);
    wtrans_kernel<<<dim3(8, 32, NL), dim3(32, 8), 0, stream>>>(Wf1, wf1t, 256, 1024, 262144, 0);
    wtrans_kernel<<<dim3(32, 8, NL), dim3(32, 8), 0, stream>>>(Wf2, wf2t, 1024, 256, 262144, 0);
    bpack_kernel<<<NL, 512, 0, stream>>>(bk1, bv1, bk2, bv2, bkv1, bkv2);

    dim3 blk(256), blk512(512);

    for (int i = 0; i < NL; ++i) {
        const short* wkv1i = wkv1t + (size_t)i * 512 * 256;
        const short* wkv2i = wkv2t + (size_t)i * 512 * 256;
        const short* wq1i = wq1t + (size_t)i * 65536;
        const short* wo1i = wo1t + (size_t)i * 65536;
        const short* wq2i = wq2t + (size_t)i * 65536;
        const short* wo2i = wo2t + (size_t)i * 65536;
        const short* wf1i = wf1t + (size_t)i * 262144;
        const short* wf2i = wf2t + (size_t)i * 262144;

        // ---- self linear-attention (x1 -> x2); trunk in A0
        gemm_bt_kernel<1><<<dim3(256, 4), blk, 0, stream>>>(A0, wkv1i, bkv1 + i * 512, BIG, 512, 256, 256, 512, 256);
        kvpart_kernel<<<dim3(NCHUNK, 64), blk, 0, stream>>>(BIG, part);
        kvred_kernel<<<64, blk, 0, stream>>>(part, kvb, ksb);
        qattn_kernel<<<M_TOTAL / 128, blk512, 0, stream>>>(A0, wq1i, bq1 + i * 256, kvb, ksb, BIG + 256);
        gemmln_kernel<0><<<M_TOTAL / 32, blk512, 0, stream>>>(BIG + 256, wo1i, bo1 + i * 256,
            ln1g + i * 256, ln1b + i * 256, A0, nullptr, A0, 256, 512);

        // ---- cross linear-attention (x2, K -> x3)
        gemm_bt_kernel<1><<<dim3(256, 4), blk, 0, stream>>>(kbf, wkv2i, bkv2 + i * 512, BIG, 512, 256, 256, 512, 256);
        kvpart_kernel<<<dim3(NCHUNK, 64), blk, 0, stream>>>(BIG, part);
        kvred_kernel<<<64, blk, 0, stream>>>(part, kvb, ksb);
        qattn_kernel<<<M_TOTAL / 128, blk512, 0, stream>>>(A0, wq2i, bq2 + i * 256, kvb, ksb, BIG + 256);
        gemmln_kernel<0><<<M_TOTAL / 32, blk512, 0, stream>>>(BIG + 256, wo2i, bo2 + i * 256,
            ln2g + i * 256, ln2b + i * 256, A0, nullptr, A0, 256, 512);

        // ---- FFN (x3 -> x1'), 2 chunks; hidden in BIG
        for (int c = 0; c < 2; ++c) {
            const size_t ro = (size_t)c * FFN_ROWS * DIM;
            gemm_bt_kernel<2><<<dim3(FFN_ROWS / 128, 8), blk, 0, stream>>>(
                A0 + ro, wf1i, bf1 + i * 1024, BIG, 1024, 256, 256, 1024, 0);
            float* foutC = (i == NL - 1) ? ((float*)d_out + ro) : nullptr;
            gemmln_kernel<2><<<FFN_ROWS / 32, blk512, 0, stream>>>(BIG, wf2i, bf2 + i * 256,
                ln3g + i * 256, ln3b + i * 256, A0 + ro, foutC, A0 + ro, 1024, 1024);
        }
    }
}